// Round 3
// baseline (1782.052 us; speedup 1.0000x reference)
//
#include <hip/hip_runtime.h>
#include <hip/hip_cooperative_groups.h>
#include <math.h>

// ---------------------------------------------------------------------------
// VMD, T = 2^20, K = 3.  u[k][t] = (f_hat[t] - lam[t]/2) * g_k(t), g_k real:
// u is never materialized.  fftshift folded into (-1)^n input modulation;
// ifftshift into (-1)^n output sign.
//
// Round-3 restructure: ALL 50 iterations run inside ONE cooperative kernel
// (256 blocks x 1024 threads, 1 block/CU).  Each thread holds its 4 complex
// points of f_hat, lam, lam_prev in REGISTERS -> per-iteration memory traffic
// is just an 8 KB partials write + grid.sync() + 8 KB broadcast read.
// lam_prev (the lambda generating output u) is written once at kernel end.
// Iteration phase runs in the six-step FFT's digit-scrambled order (freqs via
// digit swap), so no transposes between FFT and iteration phases.
// ---------------------------------------------------------------------------

#define TN        (1 << 20)
#define CNB       256         // cooperative grid: blocks
#define CNT       1024        // cooperative block: threads
#define FALPHA    2000.0f
#define FTAU      1e-7f
#define FTOL      1e-6f
#define FEPS      1e-8f
#define FTWO_PI   6.28318530717958647692f
#define FINV_T    (1.0f / 1048576.0f)

namespace cg = cooperative_groups;

__device__ __forceinline__ float2 cmulf(float2 a, float2 b) {
    return make_float2(a.x * b.x - a.y * b.y, a.x * b.y + a.y * b.x);
}
__device__ __forceinline__ float2 cisf(float a) {
    float s, c;
    sincosf(a, &s, &c);
    return make_float2(c, s);
}

// g_k(fr) for K=3 with neighbor coupling (stale omega, like the reference)
__device__ __forceinline__ void g3f(float fr, float om0, float om1, float om2,
                                    float& g0, float& g1, float& g2) {
    const float tau2 = FTAU * FTAU;
    float d0 = fr - om0; d0 *= d0;
    float d1 = fr - om1; d1 *= d1;
    float d2 = fr - om2; d2 *= d2;
    g0 = 1.0f / (1.0f + FALPHA * (d0 + d1 + tau2));
    g1 = 1.0f / (1.0f + FALPHA * (d0 + d1 + d2 + tau2));
    g2 = 1.0f / (1.0f + FALPHA * (d1 + d2 + tau2));
}

// one complex point, fully register-resident.
// lx,ly = lam_{n-1} (updated to lam_n); px,py = lam_{n-2} (updated to lam_{n-1})
__device__ __forceinline__ void vmd_pt(
    float fr, float fx, float fy,
    float& lx, float& ly, float& px, float& py, int check,
    float om0, float om1, float om2,
    float op0, float op1, float op2, float* acc) {
    float cr = fx - 0.5f * lx;
    float ci = fy - 0.5f * ly;
    float g0, g1, g2;
    g3f(fr, om0, om1, om2, g0, g1, g2);
    float m2 = cr * cr + ci * ci;
    float q0 = m2 * g0 * g0, q1 = m2 * g1 * g1, q2 = m2 * g2 * g2;
    acc[0] += q0; acc[1] += q1; acc[2] += q2;
    acc[3] += q0 * fr; acc[4] += q1 * fr; acc[5] += q2 * fr;
    if (check) {   // u_prev from lam_{n-2} (px,py) and om entering n-1
        float pr = fx - 0.5f * px;
        float pi = fy - 0.5f * py;
        float h0, h1, h2;
        g3f(fr, op0, op1, op2, h0, h1, h2);
        float ax, ay, s = 0.f;
        ax = cr * g0 - pr * h0; ay = ci * g0 - pi * h0; s += ax * ax + ay * ay;
        ax = cr * g1 - pr * h1; ay = ci * g1 - pi * h1; s += ax * ax + ay * ay;
        ax = cr * g2 - pr * h2; ay = ci * g2 - pi * h2; s += ax * ax + ay * ay;
        acc[6] += s;
        acc[7] += (pr * pr + pi * pi) * (h0 * h0 + h1 * h1 + h2 * h2);
    }
    float gs = g0 + g1 + g2;
    px = lx; py = ly;                       // lam_prev <- lam_{n-1}
    lx = lx + FTAU * (cr * gs - fx);        // lam_n
    ly = ly + FTAU * (ci * gs - fy);
}

// ---------------------------------------------------------------------------
// the whole 50-iteration VMD loop in one cooperative kernel
// ---------------------------------------------------------------------------
__global__ __launch_bounds__(CNT)
void k_vmd_all(const float2* __restrict__ fhat,
               const float* __restrict__ omega0,
               float2* __restrict__ lamOut,
               float* __restrict__ pbuf,      // 2 * 8*CNB floats
               float* __restrict__ oom) {
    cg::grid_group grid = cg::this_grid();
    const int tid  = threadIdx.x;
    const int bid  = blockIdx.x;
    const int gtid = bid * CNT + tid;        // 0 .. 262143
    const int lane = tid & 63;
    const int wid  = tid >> 6;               // 0..15

    // --- load this thread's 4 complex points of f_hat into registers ---
    const float4* __restrict__ f4 = (const float4*)fhat;
    float4 f0 = f4[gtid * 2];
    float4 f1 = f4[gtid * 2 + 1];
    // true (fftshifted) frequencies of the 4 scrambled points
    float fr[4];
#pragma unroll
    for (int j = 0; j < 4; ++j) {
        const int q = gtid * 4 + j;
        const int t = ((q & 1023) << 10) | (q >> 10);
        fr[j] = (float)t * FINV_T - 0.5f;
    }
    float4 lmA = make_float4(0.f, 0.f, 0.f, 0.f);  // lam_{n-1} (pts 0,1)
    float4 lmB = make_float4(0.f, 0.f, 0.f, 0.f);  // lam_{n-1} (pts 2,3)
    float4 lpA = make_float4(0.f, 0.f, 0.f, 0.f);  // lam_{n-2}
    float4 lpB = make_float4(0.f, 0.f, 0.f, 0.f);

    float om0 = 0.5f * omega0[0];
    float om1 = 0.5f * omega0[1];
    float om2 = 0.5f * omega0[2];
    float op0 = om0, op1 = om1, op2 = om2;   // om entering n-1

    __shared__ float  wred[16][8];
    __shared__ double dred[4][8];
    __shared__ float  bcast[4];

    for (int n = 0; n < 50; ++n) {
        if (n > 0) {
            // ---- reduce previous iteration's partials -> omega (all blocks,
            //      identical data & op order -> bitwise-identical result) ----
            const float* __restrict__ pp = pbuf + ((n - 1) & 1) * (8 * CNB);
            if (tid < CNB) {
                double d[8];
#pragma unroll
                for (int v = 0; v < 8; ++v) d[v] = (double)pp[v * CNB + tid];
#pragma unroll
                for (int off = 32; off > 0; off >>= 1) {
#pragma unroll
                    for (int v = 0; v < 8; ++v) d[v] += __shfl_down(d[v], off);
                }
                if (lane == 0) {
#pragma unroll
                    for (int v = 0; v < 8; ++v) dred[wid][v] = d[v];
                }
            }
            __syncthreads();
            if (tid == 0) {
                double s[8];
#pragma unroll
                for (int v = 0; v < 8; ++v)
                    s[v] = dred[0][v] + dred[1][v] + dred[2][v] + dred[3][v];
                const float n0 = (float)(s[3] / (s[0] + (double)FEPS));
                const float n1 = (float)(s[4] / (s[1] + (double)FEPS));
                const float n2 = (float)(s[5] / (s[2] + (double)FEPS));
                float stop = 0.f;
                if ((n - 1) % 10 == 0 && (n - 1) > 0) {  // conv eval of step n-1
                    const double ud = s[6] / (s[7] + (double)FEPS);
                    const float od = (fabsf(n0 - n2) + fabsf(n1 - n0) +
                                      fabsf(n2 - n1)) * (1.0f / 3.0f);
                    if (ud < (double)FTOL && od < FTOL) stop = 1.f;
                }
                bcast[0] = n0; bcast[1] = n1; bcast[2] = n2; bcast[3] = stop;
            }
            __syncthreads();
            if (bcast[3] != 0.f) break;      // uniform across entire grid
            op0 = om0; op1 = om1; op2 = om2;
            om0 = bcast[0]; om1 = bcast[1]; om2 = bcast[2];
        }

        const int check = (n > 0 && (n % 10) == 0) ? 1 : 0;
        float acc[8];
#pragma unroll
        for (int v = 0; v < 8; ++v) acc[v] = 0.f;

        vmd_pt(fr[0], f0.x, f0.y, lmA.x, lmA.y, lpA.x, lpA.y, check,
               om0, om1, om2, op0, op1, op2, acc);
        vmd_pt(fr[1], f0.z, f0.w, lmA.z, lmA.w, lpA.z, lpA.w, check,
               om0, om1, om2, op0, op1, op2, acc);
        vmd_pt(fr[2], f1.x, f1.y, lmB.x, lmB.y, lpB.x, lpB.y, check,
               om0, om1, om2, op0, op1, op2, acc);
        vmd_pt(fr[3], f1.z, f1.w, lmB.z, lmB.w, lpB.z, lpB.w, check,
               om0, om1, om2, op0, op1, op2, acc);

        // ---- block reduction (fixed tree -> deterministic) ----
#pragma unroll
        for (int off = 32; off > 0; off >>= 1) {
#pragma unroll
            for (int v = 0; v < 8; ++v) acc[v] += __shfl_down(acc[v], off);
        }
        if (lane == 0) {
#pragma unroll
            for (int v = 0; v < 8; ++v) wred[wid][v] = acc[v];
        }
        __syncthreads();
        if (tid < 8) {
            float s = 0.f;
#pragma unroll
            for (int w = 0; w < 16; ++w) s += wred[w][tid];
            pbuf[(n & 1) * (8 * CNB) + tid * CNB + bid] = s;
        }
        grid.sync();
    }

    // ---- output state: lam_prev + omega that generated the last u ----
    float4* __restrict__ lo4 = (float4*)lamOut;
    lo4[gtid * 2]     = lpA;
    lo4[gtid * 2 + 1] = lpB;
    if (gtid == 0) { oom[0] = om0; oom[1] = om1; oom[2] = om2; }
}

// ---------------------------------------------------------------------------
// 1024-point Stockham radix-4 stages in LDS (caller loads bufA, then syncs)
// ---------------------------------------------------------------------------
__device__ __forceinline__ float2* fft1024_stages(float2* bufA, float2* bufB,
                                                  int t, float dir) {
    float2* src = bufA;
    float2* dst = bufB;
    int Ns = 1;
#pragma unroll
    for (int s = 0; s < 5; ++s) {
        const int jm = t & (Ns - 1);
        float2 v0 = src[t], v1 = src[t + 256], v2 = src[t + 512], v3 = src[t + 768];
        const float a = dir * (FTWO_PI * 0.25f) * ((float)jm / (float)Ns);
        float2 w1 = cisf(a);
        float2 w2 = cmulf(w1, w1);
        float2 w3 = cmulf(w2, w1);
        v1 = cmulf(v1, w1); v2 = cmulf(v2, w2); v3 = cmulf(v3, w3);
        float2 s0 = make_float2(v0.x + v2.x, v0.y + v2.y);
        float2 s1 = make_float2(v0.x - v2.x, v0.y - v2.y);
        float2 s2 = make_float2(v1.x + v3.x, v1.y + v3.y);
        float2 s3 = make_float2(v1.x - v3.x, v1.y - v3.y);
        float2 s3i = make_float2(-dir * s3.y, dir * s3.x);  // dir*i * s3
        const int base = ((t - jm) << 2) + jm;
        dst[base]          = make_float2(s0.x + s2.x, s0.y + s2.y);
        dst[base + Ns]     = make_float2(s1.x + s3i.x, s1.y + s3i.y);
        dst[base + 2 * Ns] = make_float2(s0.x - s2.x, s0.y - s2.y);
        dst[base + 3 * Ns] = make_float2(s1.x - s3i.x, s1.y - s3i.y);
        __syncthreads();
        float2* tmp = src; src = dst; dst = tmp;
        Ns <<= 2;
    }
    return src;
}

// generic row FFT: dir=-1 fwd / +1 inv; do_tw: * e^{dir*2pi*i*row*col/2^20}
__global__ __launch_bounds__(256)
void k_fft1024(const float2* __restrict__ in, float2* __restrict__ out,
               float dir, int do_tw) {
    __shared__ float2 bufA[1024];
    __shared__ float2 bufB[1024];
    const int row  = blockIdx.x;
    const int rowm = row & 1023;
    const float2* __restrict__ rin  = in  + (size_t)row * 1024;
    float2* __restrict__ rout = out + (size_t)row * 1024;
    const int t = threadIdx.x;
#pragma unroll
    for (int r = 0; r < 4; ++r) bufA[t + 256 * r] = rin[t + 256 * r];
    __syncthreads();
    float2* src = fft1024_stages(bufA, bufB, t, dir);
#pragma unroll
    for (int r = 0; r < 4; ++r) {
        const int c = t + 256 * r;
        float2 xv = src[c];
        if (do_tw) {
            const unsigned p = ((unsigned)rowm * (unsigned)c) & 1048575u;
            xv = cmulf(xv, cisf(dir * (FTWO_PI * FINV_T) * (float)p));
        }
        rout[c] = xv;
    }
}

// first inverse-FFT pass with u-compute fused into the load stage.
// Scrambled row `row` of fhat/lam IS the k2-row the inverse six-step needs.
__global__ __launch_bounds__(256)
void k_fftu(const float2* __restrict__ fhat, const float2* __restrict__ lam,
            const float* __restrict__ oom,
            float2* __restrict__ out, int kbase) {
    __shared__ float2 bufA[1024];
    __shared__ float2 bufB[1024];
    const int row = blockIdx.x & 1023;
    const int z   = blockIdx.x >> 10;
    const int kk  = kbase + z;
    const float om0 = oom[0], om1 = oom[1], om2 = oom[2];
    const float2* __restrict__ frow = fhat + (size_t)row * 1024;
    const float2* __restrict__ lrow = lam  + (size_t)row * 1024;
    const int t = threadIdx.x;
#pragma unroll
    for (int r = 0; r < 4; ++r) {
        const int c = t + 256 * r;
        const float2 f  = frow[c];
        const float2 la = lrow[c];
        const float cr = f.x - 0.5f * la.x;
        const float ci = f.y - 0.5f * la.y;
        const float fr = (float)((c << 10) | row) * FINV_T - 0.5f;
        float g0, g1, g2;
        g3f(fr, om0, om1, om2, g0, g1, g2);
        const float g = (kk == 0) ? g0 : ((kk == 1) ? g1 : g2);
        bufA[c] = make_float2(cr * g, ci * g);
    }
    __syncthreads();
    float2* src = fft1024_stages(bufA, bufB, t, 1.0f);
    float2* __restrict__ rout = out + (size_t)z * TN + (size_t)row * 1024;
#pragma unroll
    for (int r = 0; r < 4; ++r) {
        const int c = t + 256 * r;
        const unsigned p = ((unsigned)row * (unsigned)c) & 1048575u;
        rout[c] = cmulf(src[c], cisf((FTWO_PI * FINV_T) * (float)p));
    }
}

// ---------------------------------------------------------------------------
// transposes (32x32 LDS tiles, block (32,8)); grid z = batch
// ---------------------------------------------------------------------------
__global__ __launch_bounds__(256)
void k_tr_c2c(const float2* __restrict__ in, float2* __restrict__ out) {
    __shared__ float2 tile[32][33];
    const size_t zo = (size_t)blockIdx.z * TN;
    const int bx = blockIdx.x * 32, by = blockIdx.y * 32;
    const int tx = threadIdx.x, ty = threadIdx.y;
#pragma unroll
    for (int j = 0; j < 32; j += 8)
        tile[ty + j][tx] = in[zo + (size_t)(by + ty + j) * 1024 + bx + tx];
    __syncthreads();
#pragma unroll
    for (int j = 0; j < 32; j += 8)
        out[zo + (size_t)(bx + ty + j) * 1024 + by + tx] = tile[tx][ty + j];
}

// forward input: y = (-1)^n * x, transposed, real -> complex
__global__ __launch_bounds__(256)
void k_tr_fwd_in(const float* __restrict__ in, float2* __restrict__ out) {
    __shared__ float tile[32][33];
    const int bx = blockIdx.x * 32, by = blockIdx.y * 32;
    const int tx = threadIdx.x, ty = threadIdx.y;
#pragma unroll
    for (int j = 0; j < 32; j += 8)
        tile[ty + j][tx] = in[(size_t)(by + ty + j) * 1024 + bx + tx];
    __syncthreads();
#pragma unroll
    for (int j = 0; j < 32; j += 8) {
        const int r = bx + ty + j;
        float v = tile[tx][ty + j];
        v = (r & 1) ? -v : v;
        out[(size_t)r * 1024 + by + tx] = make_float2(v, 0.0f);
    }
}

// inverse output: imf = (-1)^n * (1/N) * Re(.), transposed store
__global__ __launch_bounds__(256)
void k_tr_out(const float2* __restrict__ in, float* __restrict__ out) {
    __shared__ float2 tile[32][33];
    const size_t zo = (size_t)blockIdx.z * TN;
    const int bx = blockIdx.x * 32, by = blockIdx.y * 32;
    const int tx = threadIdx.x, ty = threadIdx.y;
#pragma unroll
    for (int j = 0; j < 32; j += 8)
        tile[ty + j][tx] = in[zo + (size_t)(by + ty + j) * 1024 + bx + tx];
    __syncthreads();
    const int c = by + tx;
    const float sgn = (c & 1) ? -FINV_T : FINV_T;
#pragma unroll
    for (int j = 0; j < 32; j += 8) {
        const int r = bx + ty + j;
        out[zo + (size_t)r * 1024 + c] = tile[tx][ty + j].x * sgn;
    }
}

// ---------------------------------------------------------------------------
extern "C" void kernel_launch(void* const* d_in, const int* in_sizes, int n_in,
                              void* d_out, int out_size, void* d_ws, size_t ws_size,
                              hipStream_t stream) {
    (void)in_sizes; (void)n_in; (void)out_size;
    const float* x      = (const float*)d_in[0];
    const float* omega0 = (const float*)d_in[1];
    float* outp = (float*)d_out;
    char* ws = (char*)d_ws;

    const size_t MB = (size_t)1 << 20;
    float2* fhat   = (float2*)(ws);                  // 8 MB (scrambled order)
    float2* lamOut = (float2*)(ws + 8 * MB);         // 8 MB
    float*  pbuf   = (float*)(ws + 16 * MB);         // 2 * 8*CNB floats (16 KB)
    float*  oom    = (float*)(ws + 16 * MB + 64 * 1024);  // 3 floats
    const bool batch3 = ws_size >= 66 * MB;
    float2* sA = (float2*)(ws + 17 * MB);            // 24 or 8 MB
    float2* sB = batch3 ? (float2*)(ws + 41 * MB)
                        : (float2*)(ws + 25 * MB);

    dim3 tb(32, 8);
    dim3 tg(32, 32);

    // forward FFT of (-1)^n*x -> fhat in scrambled order (4 passes)
    k_tr_fwd_in<<<tg, tb, 0, stream>>>(x, sA);
    k_fft1024<<<1024, 256, 0, stream>>>(sA, sB, -1.0f, 1);
    k_tr_c2c<<<tg, tb, 0, stream>>>(sB, sA);
    k_fft1024<<<1024, 256, 0, stream>>>(sA, fhat, -1.0f, 0);

    // all 50 VMD iterations in one cooperative kernel, state in registers
    {
        void* kargs[] = {(void*)&fhat, (void*)&omega0, (void*)&lamOut,
                         (void*)&pbuf, (void*)&oom};
        hipLaunchCooperativeKernel((const void*)k_vmd_all,
                                   dim3(CNB), dim3(CNT), kargs, 0, stream);
    }

    // inverse FFTs of u_k (u fused into first pass), output (-1)^n*Re(.)/N
    if (batch3) {
        k_fftu<<<3072, 256, 0, stream>>>(fhat, lamOut, oom, sB, 0);
        k_tr_c2c<<<dim3(32, 32, 3), tb, 0, stream>>>(sB, sA);
        k_fft1024<<<3072, 256, 0, stream>>>(sA, sB, 1.0f, 0);
        k_tr_out<<<dim3(32, 32, 3), tb, 0, stream>>>(sB, outp);
    } else {
        for (int k = 0; k < 3; ++k) {
            k_fftu<<<1024, 256, 0, stream>>>(fhat, lamOut, oom, sB, k);
            k_tr_c2c<<<tg, tb, 0, stream>>>(sB, sA);
            k_fft1024<<<1024, 256, 0, stream>>>(sA, sB, 1.0f, 0);
            k_tr_out<<<tg, tb, 0, stream>>>(sB, outp + (size_t)k * TN);
        }
    }
}

// Round 4
// 585.084 us; speedup vs baseline: 3.0458x; 3.0458x over previous
//
#include <hip/hip_runtime.h>
#include <math.h>

// ---------------------------------------------------------------------------
// VMD, T = 2^20, K = 3.  u[k][t] = (f_hat[t] - lam[t]/2) * g_k(t), g_k real:
// u is never materialized.  fftshift folded into (-1)^n input modulation;
// ifftshift into (-1)^n output sign.
//
// Round-4: persistent register-resident kernel (round 3) but grid.sync()
// (~33us/iter: full system-scope flush barrier) replaced by a hand-rolled
// barrier on agent-scope RELAXED atomics (bypass non-coherent per-XCD L2,
// complete at the coherent LLC; no cache writeback/invalidate at all).
// Per iteration: 8 atomic partial stores/block -> __syncthreads (drains vmcnt)
// -> 1 arrival atomicAdd -> all blocks spin on arrive>=256*n -> redundant
// fixed-order reduce (bitwise-identical omega everywhere).  Partials are
// double-buffered (adjacent-iteration overlap is the provable worst case).
// ---------------------------------------------------------------------------

#define TN        (1 << 20)
#define CNB       256         // cooperative grid: blocks
#define CNT       1024        // cooperative block: threads
#define FALPHA    2000.0f
#define FTAU      1e-7f
#define FTOL      1e-6f
#define FEPS      1e-8f
#define FTWO_PI   6.28318530717958647692f
#define FINV_T    (1.0f / 1048576.0f)

__device__ __forceinline__ float2 cmulf(float2 a, float2 b) {
    return make_float2(a.x * b.x - a.y * b.y, a.x * b.y + a.y * b.x);
}
__device__ __forceinline__ float2 cisf(float a) {
    float s, c;
    sincosf(a, &s, &c);
    return make_float2(c, s);
}

// g_k(fr) for K=3 with neighbor coupling (stale omega, like the reference)
__device__ __forceinline__ void g3f(float fr, float om0, float om1, float om2,
                                    float& g0, float& g1, float& g2) {
    const float tau2 = FTAU * FTAU;
    float d0 = fr - om0; d0 *= d0;
    float d1 = fr - om1; d1 *= d1;
    float d2 = fr - om2; d2 *= d2;
    g0 = 1.0f / (1.0f + FALPHA * (d0 + d1 + tau2));
    g1 = 1.0f / (1.0f + FALPHA * (d0 + d1 + d2 + tau2));
    g2 = 1.0f / (1.0f + FALPHA * (d1 + d2 + tau2));
}

// one complex point, fully register-resident.
// lx,ly = lam_{n-1} (updated to lam_n); px,py = lam_{n-2} (updated to lam_{n-1})
__device__ __forceinline__ void vmd_pt(
    float fr, float fx, float fy,
    float& lx, float& ly, float& px, float& py, int check,
    float om0, float om1, float om2,
    float op0, float op1, float op2, float* acc) {
    float cr = fx - 0.5f * lx;
    float ci = fy - 0.5f * ly;
    float g0, g1, g2;
    g3f(fr, om0, om1, om2, g0, g1, g2);
    float m2 = cr * cr + ci * ci;
    float q0 = m2 * g0 * g0, q1 = m2 * g1 * g1, q2 = m2 * g2 * g2;
    acc[0] += q0; acc[1] += q1; acc[2] += q2;
    acc[3] += q0 * fr; acc[4] += q1 * fr; acc[5] += q2 * fr;
    if (check) {   // u_prev from lam_{n-2} (px,py) and om entering n-1
        float pr = fx - 0.5f * px;
        float pi = fy - 0.5f * py;
        float h0, h1, h2;
        g3f(fr, op0, op1, op2, h0, h1, h2);
        float ax, ay, s = 0.f;
        ax = cr * g0 - pr * h0; ay = ci * g0 - pi * h0; s += ax * ax + ay * ay;
        ax = cr * g1 - pr * h1; ay = ci * g1 - pi * h1; s += ax * ax + ay * ay;
        ax = cr * g2 - pr * h2; ay = ci * g2 - pi * h2; s += ax * ax + ay * ay;
        acc[6] += s;
        acc[7] += (pr * pr + pi * pi) * (h0 * h0 + h1 * h1 + h2 * h2);
    }
    float gs = g0 + g1 + g2;
    px = lx; py = ly;                       // lam_prev <- lam_{n-1}
    lx = lx + FTAU * (cr * gs - fx);        // lam_n
    ly = ly + FTAU * (ci * gs - fy);
}

// zero the arrival counter (ws is re-poisoned to 0xAA before every call)
__global__ __launch_bounds__(64)
void k_init0(unsigned* __restrict__ arrive) {
    if (threadIdx.x == 0) *arrive = 0u;
}

// ---------------------------------------------------------------------------
// the whole 50-iteration VMD loop in one cooperative kernel, custom barrier
// ---------------------------------------------------------------------------
__global__ __launch_bounds__(CNT)
void k_vmd_all(const float2* __restrict__ fhat,
               const float* __restrict__ omega0,
               float2* __restrict__ lamOut,
               float* __restrict__ pbuf,      // 2 slots * 8*CNB floats
               unsigned* __restrict__ arrive,
               float* __restrict__ oom) {
    const int tid  = threadIdx.x;
    const int bid  = blockIdx.x;
    const int gtid = bid * CNT + tid;        // 0 .. 262143
    const int lane = tid & 63;
    const int wid  = tid >> 6;               // 0..15

    // --- load this thread's 4 complex points of f_hat into registers ---
    const float4* __restrict__ f4 = (const float4*)fhat;
    float4 f0 = f4[gtid * 2];
    float4 f1 = f4[gtid * 2 + 1];
    // true (fftshifted) frequencies of the 4 scrambled points
    float fr[4];
#pragma unroll
    for (int j = 0; j < 4; ++j) {
        const int q = gtid * 4 + j;
        const int t = ((q & 1023) << 10) | (q >> 10);
        fr[j] = (float)t * FINV_T - 0.5f;
    }
    float4 lmA = make_float4(0.f, 0.f, 0.f, 0.f);  // lam_{n-1} (pts 0,1)
    float4 lmB = make_float4(0.f, 0.f, 0.f, 0.f);  // lam_{n-1} (pts 2,3)
    float4 lpA = make_float4(0.f, 0.f, 0.f, 0.f);  // lam_{n-2}
    float4 lpB = make_float4(0.f, 0.f, 0.f, 0.f);

    float om0 = 0.5f * omega0[0];
    float om1 = 0.5f * omega0[1];
    float om2 = 0.5f * omega0[2];
    float op0 = om0, op1 = om1, op2 = om2;   // om entering n-1

    __shared__ float  wred[16][8];
    __shared__ double dred[4][8];
    __shared__ float  bcast[4];

    for (int n = 0; n < 50; ++n) {
        if (n > 0) {
            // ---- wait for all 256 blocks to have finished iteration n-1 ----
            if (tid == 0) {
                const unsigned tgt = (unsigned)(CNB * n);
                while (__hip_atomic_load(arrive, __ATOMIC_RELAXED,
                                         __HIP_MEMORY_SCOPE_AGENT) < tgt)
                    __builtin_amdgcn_s_sleep(1);
            }
            __syncthreads();
            // ---- redundant fixed-order reduce of 8x256 partials -> omega ----
            const float* __restrict__ pp = pbuf + ((n - 1) & 1) * (8 * CNB);
            if (tid < CNB) {
                double d[8];
#pragma unroll
                for (int v = 0; v < 8; ++v)
                    d[v] = (double)__hip_atomic_load(&pp[v * CNB + tid],
                                                     __ATOMIC_RELAXED,
                                                     __HIP_MEMORY_SCOPE_AGENT);
#pragma unroll
                for (int off = 32; off > 0; off >>= 1) {
#pragma unroll
                    for (int v = 0; v < 8; ++v) d[v] += __shfl_down(d[v], off);
                }
                if (lane == 0) {
#pragma unroll
                    for (int v = 0; v < 8; ++v) dred[wid][v] = d[v];
                }
            }
            __syncthreads();
            if (tid == 0) {
                double s[8];
#pragma unroll
                for (int v = 0; v < 8; ++v)
                    s[v] = dred[0][v] + dred[1][v] + dred[2][v] + dred[3][v];
                const float n0 = (float)(s[3] / (s[0] + (double)FEPS));
                const float n1 = (float)(s[4] / (s[1] + (double)FEPS));
                const float n2 = (float)(s[5] / (s[2] + (double)FEPS));
                float stop = 0.f;
                if ((n - 1) % 10 == 0 && (n - 1) > 0) {  // conv eval of step n-1
                    const double ud = s[6] / (s[7] + (double)FEPS);
                    const float od = (fabsf(n0 - n2) + fabsf(n1 - n0) +
                                      fabsf(n2 - n1)) * (1.0f / 3.0f);
                    if (ud < (double)FTOL && od < FTOL) stop = 1.f;
                }
                bcast[0] = n0; bcast[1] = n1; bcast[2] = n2; bcast[3] = stop;
            }
            __syncthreads();
            if (bcast[3] != 0.f) break;      // identical decision in all blocks
            op0 = om0; op1 = om1; op2 = om2;
            om0 = bcast[0]; om1 = bcast[1]; om2 = bcast[2];
        }

        const int check = (n > 0 && (n % 10) == 0) ? 1 : 0;
        float acc[8];
#pragma unroll
        for (int v = 0; v < 8; ++v) acc[v] = 0.f;

        vmd_pt(fr[0], f0.x, f0.y, lmA.x, lmA.y, lpA.x, lpA.y, check,
               om0, om1, om2, op0, op1, op2, acc);
        vmd_pt(fr[1], f0.z, f0.w, lmA.z, lmA.w, lpA.z, lpA.w, check,
               om0, om1, om2, op0, op1, op2, acc);
        vmd_pt(fr[2], f1.x, f1.y, lmB.x, lmB.y, lpB.x, lpB.y, check,
               om0, om1, om2, op0, op1, op2, acc);
        vmd_pt(fr[3], f1.z, f1.w, lmB.z, lmB.w, lpB.z, lpB.w, check,
               om0, om1, om2, op0, op1, op2, acc);

        // ---- block reduction (fixed tree -> deterministic) ----
#pragma unroll
        for (int off = 32; off > 0; off >>= 1) {
#pragma unroll
            for (int v = 0; v < 8; ++v) acc[v] += __shfl_down(acc[v], off);
        }
        if (lane == 0) {
#pragma unroll
            for (int v = 0; v < 8; ++v) wred[wid][v] = acc[v];
        }
        __syncthreads();
        if (tid < 8) {
            float s = 0.f;
#pragma unroll
            for (int w = 0; w < 16; ++w) s += wred[w][tid];
            __hip_atomic_store(&pbuf[(n & 1) * (8 * CNB) + tid * CNB + bid], s,
                               __ATOMIC_RELAXED, __HIP_MEMORY_SCOPE_AGENT);
        }
        __syncthreads();   // drains vmcnt: partial stores at LLC before arrival
        if (tid == 0)
            __hip_atomic_fetch_add(arrive, 1u, __ATOMIC_RELAXED,
                                   __HIP_MEMORY_SCOPE_AGENT);
    }

    // ---- output state: lam_prev + omega that generated the last u ----
    float4* __restrict__ lo4 = (float4*)lamOut;
    lo4[gtid * 2]     = lpA;
    lo4[gtid * 2 + 1] = lpB;
    if (gtid == 0) { oom[0] = om0; oom[1] = om1; oom[2] = om2; }
}

// ---------------------------------------------------------------------------
// 1024-point Stockham radix-4 stages in LDS (caller loads bufA, then syncs)
// ---------------------------------------------------------------------------
__device__ __forceinline__ float2* fft1024_stages(float2* bufA, float2* bufB,
                                                  int t, float dir) {
    float2* src = bufA;
    float2* dst = bufB;
    int Ns = 1;
#pragma unroll
    for (int s = 0; s < 5; ++s) {
        const int jm = t & (Ns - 1);
        float2 v0 = src[t], v1 = src[t + 256], v2 = src[t + 512], v3 = src[t + 768];
        const float a = dir * (FTWO_PI * 0.25f) * ((float)jm / (float)Ns);
        float2 w1 = cisf(a);
        float2 w2 = cmulf(w1, w1);
        float2 w3 = cmulf(w2, w1);
        v1 = cmulf(v1, w1); v2 = cmulf(v2, w2); v3 = cmulf(v3, w3);
        float2 s0 = make_float2(v0.x + v2.x, v0.y + v2.y);
        float2 s1 = make_float2(v0.x - v2.x, v0.y - v2.y);
        float2 s2 = make_float2(v1.x + v3.x, v1.y + v3.y);
        float2 s3 = make_float2(v1.x - v3.x, v1.y - v3.y);
        float2 s3i = make_float2(-dir * s3.y, dir * s3.x);  // dir*i * s3
        const int base = ((t - jm) << 2) + jm;
        dst[base]          = make_float2(s0.x + s2.x, s0.y + s2.y);
        dst[base + Ns]     = make_float2(s1.x + s3i.x, s1.y + s3i.y);
        dst[base + 2 * Ns] = make_float2(s0.x - s2.x, s0.y - s2.y);
        dst[base + 3 * Ns] = make_float2(s1.x - s3i.x, s1.y - s3i.y);
        __syncthreads();
        float2* tmp = src; src = dst; dst = tmp;
        Ns <<= 2;
    }
    return src;
}

// generic row FFT: dir=-1 fwd / +1 inv; do_tw: * e^{dir*2pi*i*row*col/2^20}
__global__ __launch_bounds__(256)
void k_fft1024(const float2* __restrict__ in, float2* __restrict__ out,
               float dir, int do_tw) {
    __shared__ float2 bufA[1024];
    __shared__ float2 bufB[1024];
    const int row  = blockIdx.x;
    const int rowm = row & 1023;
    const float2* __restrict__ rin  = in  + (size_t)row * 1024;
    float2* __restrict__ rout = out + (size_t)row * 1024;
    const int t = threadIdx.x;
#pragma unroll
    for (int r = 0; r < 4; ++r) bufA[t + 256 * r] = rin[t + 256 * r];
    __syncthreads();
    float2* src = fft1024_stages(bufA, bufB, t, dir);
#pragma unroll
    for (int r = 0; r < 4; ++r) {
        const int c = t + 256 * r;
        float2 xv = src[c];
        if (do_tw) {
            const unsigned p = ((unsigned)rowm * (unsigned)c) & 1048575u;
            xv = cmulf(xv, cisf(dir * (FTWO_PI * FINV_T) * (float)p));
        }
        rout[c] = xv;
    }
}

// first inverse-FFT pass with u-compute fused into the load stage.
// Scrambled row `row` of fhat/lam IS the k2-row the inverse six-step needs.
__global__ __launch_bounds__(256)
void k_fftu(const float2* __restrict__ fhat, const float2* __restrict__ lam,
            const float* __restrict__ oom,
            float2* __restrict__ out, int kbase) {
    __shared__ float2 bufA[1024];
    __shared__ float2 bufB[1024];
    const int row = blockIdx.x & 1023;
    const int z   = blockIdx.x >> 10;
    const int kk  = kbase + z;
    const float om0 = oom[0], om1 = oom[1], om2 = oom[2];
    const float2* __restrict__ frow = fhat + (size_t)row * 1024;
    const float2* __restrict__ lrow = lam  + (size_t)row * 1024;
    const int t = threadIdx.x;
#pragma unroll
    for (int r = 0; r < 4; ++r) {
        const int c = t + 256 * r;
        const float2 f  = frow[c];
        const float2 la = lrow[c];
        const float cr = f.x - 0.5f * la.x;
        const float ci = f.y - 0.5f * la.y;
        const float fr = (float)((c << 10) | row) * FINV_T - 0.5f;
        float g0, g1, g2;
        g3f(fr, om0, om1, om2, g0, g1, g2);
        const float g = (kk == 0) ? g0 : ((kk == 1) ? g1 : g2);
        bufA[c] = make_float2(cr * g, ci * g);
    }
    __syncthreads();
    float2* src = fft1024_stages(bufA, bufB, t, 1.0f);
    float2* __restrict__ rout = out + (size_t)z * TN + (size_t)row * 1024;
#pragma unroll
    for (int r = 0; r < 4; ++r) {
        const int c = t + 256 * r;
        const unsigned p = ((unsigned)row * (unsigned)c) & 1048575u;
        rout[c] = cmulf(src[c], cisf((FTWO_PI * FINV_T) * (float)p));
    }
}

// ---------------------------------------------------------------------------
// transposes (32x32 LDS tiles, block (32,8)); grid z = batch
// ---------------------------------------------------------------------------
__global__ __launch_bounds__(256)
void k_tr_c2c(const float2* __restrict__ in, float2* __restrict__ out) {
    __shared__ float2 tile[32][33];
    const size_t zo = (size_t)blockIdx.z * TN;
    const int bx = blockIdx.x * 32, by = blockIdx.y * 32;
    const int tx = threadIdx.x, ty = threadIdx.y;
#pragma unroll
    for (int j = 0; j < 32; j += 8)
        tile[ty + j][tx] = in[zo + (size_t)(by + ty + j) * 1024 + bx + tx];
    __syncthreads();
#pragma unroll
    for (int j = 0; j < 32; j += 8)
        out[zo + (size_t)(bx + ty + j) * 1024 + by + tx] = tile[tx][ty + j];
}

// forward input: y = (-1)^n * x, transposed, real -> complex
__global__ __launch_bounds__(256)
void k_tr_fwd_in(const float* __restrict__ in, float2* __restrict__ out) {
    __shared__ float tile[32][33];
    const int bx = blockIdx.x * 32, by = blockIdx.y * 32;
    const int tx = threadIdx.x, ty = threadIdx.y;
#pragma unroll
    for (int j = 0; j < 32; j += 8)
        tile[ty + j][tx] = in[(size_t)(by + ty + j) * 1024 + bx + tx];
    __syncthreads();
#pragma unroll
    for (int j = 0; j < 32; j += 8) {
        const int r = bx + ty + j;
        float v = tile[tx][ty + j];
        v = (r & 1) ? -v : v;
        out[(size_t)r * 1024 + by + tx] = make_float2(v, 0.0f);
    }
}

// inverse output: imf = (-1)^n * (1/N) * Re(.), transposed store
__global__ __launch_bounds__(256)
void k_tr_out(const float2* __restrict__ in, float* __restrict__ out) {
    __shared__ float2 tile[32][33];
    const size_t zo = (size_t)blockIdx.z * TN;
    const int bx = blockIdx.x * 32, by = blockIdx.y * 32;
    const int tx = threadIdx.x, ty = threadIdx.y;
#pragma unroll
    for (int j = 0; j < 32; j += 8)
        tile[ty + j][tx] = in[zo + (size_t)(by + ty + j) * 1024 + bx + tx];
    __syncthreads();
    const int c = by + tx;
    const float sgn = (c & 1) ? -FINV_T : FINV_T;
#pragma unroll
    for (int j = 0; j < 32; j += 8) {
        const int r = bx + ty + j;
        out[zo + (size_t)r * 1024 + c] = tile[tx][ty + j].x * sgn;
    }
}

// ---------------------------------------------------------------------------
extern "C" void kernel_launch(void* const* d_in, const int* in_sizes, int n_in,
                              void* d_out, int out_size, void* d_ws, size_t ws_size,
                              hipStream_t stream) {
    (void)in_sizes; (void)n_in; (void)out_size;
    const float* x      = (const float*)d_in[0];
    const float* omega0 = (const float*)d_in[1];
    float* outp = (float*)d_out;
    char* ws = (char*)d_ws;

    const size_t MB = (size_t)1 << 20;
    float2* fhat   = (float2*)(ws);                  // 8 MB (scrambled order)
    float2* lamOut = (float2*)(ws + 8 * MB);         // 8 MB
    float*  pbuf   = (float*)(ws + 16 * MB);         // 2 slots * 8*CNB (16 KB)
    unsigned* arrive = (unsigned*)(ws + 16 * MB + 64 * 1024);
    float*  oom    = (float*)(ws + 16 * MB + 64 * 1024 + 256);  // 3 floats
    const bool batch3 = ws_size >= 66 * MB;
    float2* sA = (float2*)(ws + 17 * MB);            // 24 or 8 MB
    float2* sB = batch3 ? (float2*)(ws + 41 * MB)
                        : (float2*)(ws + 25 * MB);

    dim3 tb(32, 8);
    dim3 tg(32, 32);

    k_init0<<<1, 64, 0, stream>>>(arrive);

    // forward FFT of (-1)^n*x -> fhat in scrambled order (4 passes)
    k_tr_fwd_in<<<tg, tb, 0, stream>>>(x, sA);
    k_fft1024<<<1024, 256, 0, stream>>>(sA, sB, -1.0f, 1);
    k_tr_c2c<<<tg, tb, 0, stream>>>(sB, sA);
    k_fft1024<<<1024, 256, 0, stream>>>(sA, fhat, -1.0f, 0);

    // all 50 VMD iterations in one cooperative kernel, state in registers
    {
        void* kargs[] = {(void*)&fhat, (void*)&omega0, (void*)&lamOut,
                         (void*)&pbuf, (void*)&arrive, (void*)&oom};
        hipLaunchCooperativeKernel((const void*)k_vmd_all,
                                   dim3(CNB), dim3(CNT), kargs, 0, stream);
    }

    // inverse FFTs of u_k (u fused into first pass), output (-1)^n*Re(.)/N
    if (batch3) {
        k_fftu<<<3072, 256, 0, stream>>>(fhat, lamOut, oom, sB, 0);
        k_tr_c2c<<<dim3(32, 32, 3), tb, 0, stream>>>(sB, sA);
        k_fft1024<<<3072, 256, 0, stream>>>(sA, sB, 1.0f, 0);
        k_tr_out<<<dim3(32, 32, 3), tb, 0, stream>>>(sB, outp);
    } else {
        for (int k = 0; k < 3; ++k) {
            k_fftu<<<1024, 256, 0, stream>>>(fhat, lamOut, oom, sB, k);
            k_tr_c2c<<<tg, tb, 0, stream>>>(sB, sA);
            k_fft1024<<<1024, 256, 0, stream>>>(sA, sB, 1.0f, 0);
            k_tr_out<<<tg, tb, 0, stream>>>(sB, outp + (size_t)k * TN);
        }
    }
}

// Round 5
// 486.440 us; speedup vs baseline: 3.6635x; 1.2028x over previous
//
#include <hip/hip_runtime.h>
#include <math.h>

// ---------------------------------------------------------------------------
// VMD, T = 2^20, K = 3.  u[k][t] = (f_hat[t] - lam[t]/2) * g_k(t), g_k real:
// u is never materialized.  fftshift folded into (-1)^n input modulation;
// ifftshift into (-1)^n output sign.
//
// Round-5: persistent register-resident cooperative kernel with a
// CONTENTION-FREE epoch-flag barrier.  Round 4's single arrival counter was
// simultaneously a 256-way serialized atomicAdd chain and the spin target of
// 256 polling waves -> reads queued against RMWs at the LLC (~7us/iter).
// Now each block publishes flags[bid] = n+1 (relaxed agent store, no RMW);
// wave 0 of every block polls all 256 flags with 4 coalesced agent loads per
// lane + __all.  Partials stay double-buffered; write->__syncthreads (vmcnt
// drain)->flag preserves the ordering pattern validated in round 4.
// ---------------------------------------------------------------------------

#define TN        (1 << 20)
#define CNB       256         // cooperative grid: blocks
#define CNT       1024        // cooperative block: threads
#define FALPHA    2000.0f
#define FTAU      1e-7f
#define FTOL      1e-6f
#define FEPS      1e-8f
#define FTWO_PI   6.28318530717958647692f
#define FINV_T    (1.0f / 1048576.0f)

__device__ __forceinline__ float2 cmulf(float2 a, float2 b) {
    return make_float2(a.x * b.x - a.y * b.y, a.x * b.y + a.y * b.x);
}
__device__ __forceinline__ float2 cisf(float a) {
    float s, c;
    sincosf(a, &s, &c);
    return make_float2(c, s);
}

// g_k(fr) for K=3 with neighbor coupling (stale omega, like the reference)
__device__ __forceinline__ void g3f(float fr, float om0, float om1, float om2,
                                    float& g0, float& g1, float& g2) {
    const float tau2 = FTAU * FTAU;
    float d0 = fr - om0; d0 *= d0;
    float d1 = fr - om1; d1 *= d1;
    float d2 = fr - om2; d2 *= d2;
    g0 = 1.0f / (1.0f + FALPHA * (d0 + d1 + tau2));
    g1 = 1.0f / (1.0f + FALPHA * (d0 + d1 + d2 + tau2));
    g2 = 1.0f / (1.0f + FALPHA * (d1 + d2 + tau2));
}

// one complex point, fully register-resident.
// lx,ly = lam_{n-1} (updated to lam_n); px,py = lam_{n-2} (updated to lam_{n-1})
__device__ __forceinline__ void vmd_pt(
    float fr, float fx, float fy,
    float& lx, float& ly, float& px, float& py, int check,
    float om0, float om1, float om2,
    float op0, float op1, float op2, float* acc) {
    float cr = fx - 0.5f * lx;
    float ci = fy - 0.5f * ly;
    float g0, g1, g2;
    g3f(fr, om0, om1, om2, g0, g1, g2);
    float m2 = cr * cr + ci * ci;
    float q0 = m2 * g0 * g0, q1 = m2 * g1 * g1, q2 = m2 * g2 * g2;
    acc[0] += q0; acc[1] += q1; acc[2] += q2;
    acc[3] += q0 * fr; acc[4] += q1 * fr; acc[5] += q2 * fr;
    if (check) {   // u_prev from lam_{n-2} (px,py) and om entering n-1
        float pr = fx - 0.5f * px;
        float pi = fy - 0.5f * py;
        float h0, h1, h2;
        g3f(fr, op0, op1, op2, h0, h1, h2);
        float ax, ay, s = 0.f;
        ax = cr * g0 - pr * h0; ay = ci * g0 - pi * h0; s += ax * ax + ay * ay;
        ax = cr * g1 - pr * h1; ay = ci * g1 - pi * h1; s += ax * ax + ay * ay;
        ax = cr * g2 - pr * h2; ay = ci * g2 - pi * h2; s += ax * ax + ay * ay;
        acc[6] += s;
        acc[7] += (pr * pr + pi * pi) * (h0 * h0 + h1 * h1 + h2 * h2);
    }
    float gs = g0 + g1 + g2;
    px = lx; py = ly;                       // lam_prev <- lam_{n-1}
    lx = lx + FTAU * (cr * gs - fx);        // lam_n
    ly = ly + FTAU * (ci * gs - fy);
}

// zero the epoch flags (ws is re-poisoned to 0xAA before every timed launch)
__global__ __launch_bounds__(CNB)
void k_init0(unsigned* __restrict__ flags) {
    flags[threadIdx.x] = 0u;
}

// ---------------------------------------------------------------------------
// the whole 50-iteration VMD loop in one cooperative kernel, flag barrier
// ---------------------------------------------------------------------------
__global__ __launch_bounds__(CNT)
void k_vmd_all(const float2* __restrict__ fhat,
               const float* __restrict__ omega0,
               float2* __restrict__ lamOut,
               float* __restrict__ pbuf,      // 2 slots * 8*CNB floats
               unsigned* __restrict__ flags,  // CNB epoch flags
               float* __restrict__ oom) {
    const int tid  = threadIdx.x;
    const int bid  = blockIdx.x;
    const int gtid = bid * CNT + tid;        // 0 .. 262143
    const int lane = tid & 63;
    const int wid  = tid >> 6;               // 0..15

    // --- load this thread's 4 complex points of f_hat into registers ---
    const float4* __restrict__ f4 = (const float4*)fhat;
    float4 f0 = f4[gtid * 2];
    float4 f1 = f4[gtid * 2 + 1];
    // true (fftshifted) frequencies of the 4 scrambled points
    float fr[4];
#pragma unroll
    for (int j = 0; j < 4; ++j) {
        const int q = gtid * 4 + j;
        const int t = ((q & 1023) << 10) | (q >> 10);
        fr[j] = (float)t * FINV_T - 0.5f;
    }
    float4 lmA = make_float4(0.f, 0.f, 0.f, 0.f);  // lam_{n-1} (pts 0,1)
    float4 lmB = make_float4(0.f, 0.f, 0.f, 0.f);  // lam_{n-1} (pts 2,3)
    float4 lpA = make_float4(0.f, 0.f, 0.f, 0.f);  // lam_{n-2}
    float4 lpB = make_float4(0.f, 0.f, 0.f, 0.f);

    float om0 = 0.5f * omega0[0];
    float om1 = 0.5f * omega0[1];
    float om2 = 0.5f * omega0[2];
    float op0 = om0, op1 = om1, op2 = om2;   // om entering n-1

    __shared__ float  wred[16][8];
    __shared__ double dred[4][8];
    __shared__ float  bcast[4];

    for (int n = 0; n < 50; ++n) {
        if (n > 0) {
            // ---- wait until every block published iteration n-1 ----
            if (wid == 0) {
                const unsigned tgt = (unsigned)n;
                for (;;) {
                    unsigned a = __hip_atomic_load(&flags[lane],
                                   __ATOMIC_RELAXED, __HIP_MEMORY_SCOPE_AGENT);
                    unsigned b = __hip_atomic_load(&flags[lane + 64],
                                   __ATOMIC_RELAXED, __HIP_MEMORY_SCOPE_AGENT);
                    unsigned c = __hip_atomic_load(&flags[lane + 128],
                                   __ATOMIC_RELAXED, __HIP_MEMORY_SCOPE_AGENT);
                    unsigned d = __hip_atomic_load(&flags[lane + 192],
                                   __ATOMIC_RELAXED, __HIP_MEMORY_SCOPE_AGENT);
                    unsigned m = min(min(a, b), min(c, d));
                    if (__all(m >= tgt)) break;
                }
            }
            __syncthreads();
            // ---- redundant fixed-order reduce of 8x256 partials -> omega ----
            const float* __restrict__ pp = pbuf + ((n - 1) & 1) * (8 * CNB);
            if (tid < CNB) {
                double d[8];
#pragma unroll
                for (int v = 0; v < 8; ++v)
                    d[v] = (double)__hip_atomic_load(&pp[v * CNB + tid],
                                                     __ATOMIC_RELAXED,
                                                     __HIP_MEMORY_SCOPE_AGENT);
#pragma unroll
                for (int off = 32; off > 0; off >>= 1) {
#pragma unroll
                    for (int v = 0; v < 8; ++v) d[v] += __shfl_down(d[v], off);
                }
                if (lane == 0) {
#pragma unroll
                    for (int v = 0; v < 8; ++v) dred[wid][v] = d[v];
                }
            }
            __syncthreads();
            if (tid == 0) {
                double s[8];
#pragma unroll
                for (int v = 0; v < 8; ++v)
                    s[v] = dred[0][v] + dred[1][v] + dred[2][v] + dred[3][v];
                const float n0 = (float)(s[3] / (s[0] + (double)FEPS));
                const float n1 = (float)(s[4] / (s[1] + (double)FEPS));
                const float n2 = (float)(s[5] / (s[2] + (double)FEPS));
                float stop = 0.f;
                if ((n - 1) % 10 == 0 && (n - 1) > 0) {  // conv eval of step n-1
                    const double ud = s[6] / (s[7] + (double)FEPS);
                    const float od = (fabsf(n0 - n2) + fabsf(n1 - n0) +
                                      fabsf(n2 - n1)) * (1.0f / 3.0f);
                    if (ud < (double)FTOL && od < FTOL) stop = 1.f;
                }
                bcast[0] = n0; bcast[1] = n1; bcast[2] = n2; bcast[3] = stop;
            }
            __syncthreads();
            if (bcast[3] != 0.f) break;      // identical decision in all blocks
            op0 = om0; op1 = om1; op2 = om2;
            om0 = bcast[0]; om1 = bcast[1]; om2 = bcast[2];
        }

        const int check = (n > 0 && (n % 10) == 0) ? 1 : 0;
        float acc[8];
#pragma unroll
        for (int v = 0; v < 8; ++v) acc[v] = 0.f;

        vmd_pt(fr[0], f0.x, f0.y, lmA.x, lmA.y, lpA.x, lpA.y, check,
               om0, om1, om2, op0, op1, op2, acc);
        vmd_pt(fr[1], f0.z, f0.w, lmA.z, lmA.w, lpA.z, lpA.w, check,
               om0, om1, om2, op0, op1, op2, acc);
        vmd_pt(fr[2], f1.x, f1.y, lmB.x, lmB.y, lpB.x, lpB.y, check,
               om0, om1, om2, op0, op1, op2, acc);
        vmd_pt(fr[3], f1.z, f1.w, lmB.z, lmB.w, lpB.z, lpB.w, check,
               om0, om1, om2, op0, op1, op2, acc);

        // ---- block reduction (fixed tree -> deterministic) ----
#pragma unroll
        for (int off = 32; off > 0; off >>= 1) {
#pragma unroll
            for (int v = 0; v < 8; ++v) acc[v] += __shfl_down(acc[v], off);
        }
        if (lane == 0) {
#pragma unroll
            for (int v = 0; v < 8; ++v) wred[wid][v] = acc[v];
        }
        __syncthreads();
        if (tid < 8) {
            float s = 0.f;
#pragma unroll
            for (int w = 0; w < 16; ++w) s += wred[w][tid];
            __hip_atomic_store(&pbuf[(n & 1) * (8 * CNB) + tid * CNB + bid], s,
                               __ATOMIC_RELAXED, __HIP_MEMORY_SCOPE_AGENT);
        }
        __syncthreads();   // drains vmcnt: partial stores at LLC before flag
        if (tid == 0)
            __hip_atomic_store(&flags[bid], (unsigned)(n + 1),
                               __ATOMIC_RELAXED, __HIP_MEMORY_SCOPE_AGENT);
    }

    // ---- output state: lam_prev + omega that generated the last u ----
    float4* __restrict__ lo4 = (float4*)lamOut;
    lo4[gtid * 2]     = lpA;
    lo4[gtid * 2 + 1] = lpB;
    if (gtid == 0) { oom[0] = om0; oom[1] = om1; oom[2] = om2; }
}

// ---------------------------------------------------------------------------
// 1024-point Stockham radix-4 stages in LDS (caller loads bufA, then syncs)
// ---------------------------------------------------------------------------
__device__ __forceinline__ float2* fft1024_stages(float2* bufA, float2* bufB,
                                                  int t, float dir) {
    float2* src = bufA;
    float2* dst = bufB;
    int Ns = 1;
#pragma unroll
    for (int s = 0; s < 5; ++s) {
        const int jm = t & (Ns - 1);
        float2 v0 = src[t], v1 = src[t + 256], v2 = src[t + 512], v3 = src[t + 768];
        const float a = dir * (FTWO_PI * 0.25f) * ((float)jm / (float)Ns);
        float2 w1 = cisf(a);
        float2 w2 = cmulf(w1, w1);
        float2 w3 = cmulf(w2, w1);
        v1 = cmulf(v1, w1); v2 = cmulf(v2, w2); v3 = cmulf(v3, w3);
        float2 s0 = make_float2(v0.x + v2.x, v0.y + v2.y);
        float2 s1 = make_float2(v0.x - v2.x, v0.y - v2.y);
        float2 s2 = make_float2(v1.x + v3.x, v1.y + v3.y);
        float2 s3 = make_float2(v1.x - v3.x, v1.y - v3.y);
        float2 s3i = make_float2(-dir * s3.y, dir * s3.x);  // dir*i * s3
        const int base = ((t - jm) << 2) + jm;
        dst[base]          = make_float2(s0.x + s2.x, s0.y + s2.y);
        dst[base + Ns]     = make_float2(s1.x + s3i.x, s1.y + s3i.y);
        dst[base + 2 * Ns] = make_float2(s0.x - s2.x, s0.y - s2.y);
        dst[base + 3 * Ns] = make_float2(s1.x - s3i.x, s1.y - s3i.y);
        __syncthreads();
        float2* tmp = src; src = dst; dst = tmp;
        Ns <<= 2;
    }
    return src;
}

// generic row FFT: dir=-1 fwd / +1 inv; do_tw: * e^{dir*2pi*i*row*col/2^20}
__global__ __launch_bounds__(256)
void k_fft1024(const float2* __restrict__ in, float2* __restrict__ out,
               float dir, int do_tw) {
    __shared__ float2 bufA[1024];
    __shared__ float2 bufB[1024];
    const int row  = blockIdx.x;
    const int rowm = row & 1023;
    const float2* __restrict__ rin  = in  + (size_t)row * 1024;
    float2* __restrict__ rout = out + (size_t)row * 1024;
    const int t = threadIdx.x;
#pragma unroll
    for (int r = 0; r < 4; ++r) bufA[t + 256 * r] = rin[t + 256 * r];
    __syncthreads();
    float2* src = fft1024_stages(bufA, bufB, t, dir);
#pragma unroll
    for (int r = 0; r < 4; ++r) {
        const int c = t + 256 * r;
        float2 xv = src[c];
        if (do_tw) {
            const unsigned p = ((unsigned)rowm * (unsigned)c) & 1048575u;
            xv = cmulf(xv, cisf(dir * (FTWO_PI * FINV_T) * (float)p));
        }
        rout[c] = xv;
    }
}

// first inverse-FFT pass with u-compute fused into the load stage.
// Scrambled row `row` of fhat/lam IS the k2-row the inverse six-step needs.
__global__ __launch_bounds__(256)
void k_fftu(const float2* __restrict__ fhat, const float2* __restrict__ lam,
            const float* __restrict__ oom,
            float2* __restrict__ out, int kbase) {
    __shared__ float2 bufA[1024];
    __shared__ float2 bufB[1024];
    const int row = blockIdx.x & 1023;
    const int z   = blockIdx.x >> 10;
    const int kk  = kbase + z;
    const float om0 = oom[0], om1 = oom[1], om2 = oom[2];
    const float2* __restrict__ frow = fhat + (size_t)row * 1024;
    const float2* __restrict__ lrow = lam  + (size_t)row * 1024;
    const int t = threadIdx.x;
#pragma unroll
    for (int r = 0; r < 4; ++r) {
        const int c = t + 256 * r;
        const float2 f  = frow[c];
        const float2 la = lrow[c];
        const float cr = f.x - 0.5f * la.x;
        const float ci = f.y - 0.5f * la.y;
        const float fr = (float)((c << 10) | row) * FINV_T - 0.5f;
        float g0, g1, g2;
        g3f(fr, om0, om1, om2, g0, g1, g2);
        const float g = (kk == 0) ? g0 : ((kk == 1) ? g1 : g2);
        bufA[c] = make_float2(cr * g, ci * g);
    }
    __syncthreads();
    float2* src = fft1024_stages(bufA, bufB, t, 1.0f);
    float2* __restrict__ rout = out + (size_t)z * TN + (size_t)row * 1024;
#pragma unroll
    for (int r = 0; r < 4; ++r) {
        const int c = t + 256 * r;
        const unsigned p = ((unsigned)row * (unsigned)c) & 1048575u;
        rout[c] = cmulf(src[c], cisf((FTWO_PI * FINV_T) * (float)p));
    }
}

// ---------------------------------------------------------------------------
// transposes (32x32 LDS tiles, block (32,8)); grid z = batch
// ---------------------------------------------------------------------------
__global__ __launch_bounds__(256)
void k_tr_c2c(const float2* __restrict__ in, float2* __restrict__ out) {
    __shared__ float2 tile[32][33];
    const size_t zo = (size_t)blockIdx.z * TN;
    const int bx = blockIdx.x * 32, by = blockIdx.y * 32;
    const int tx = threadIdx.x, ty = threadIdx.y;
#pragma unroll
    for (int j = 0; j < 32; j += 8)
        tile[ty + j][tx] = in[zo + (size_t)(by + ty + j) * 1024 + bx + tx];
    __syncthreads();
#pragma unroll
    for (int j = 0; j < 32; j += 8)
        out[zo + (size_t)(bx + ty + j) * 1024 + by + tx] = tile[tx][ty + j];
}

// forward input: y = (-1)^n * x, transposed, real -> complex
__global__ __launch_bounds__(256)
void k_tr_fwd_in(const float* __restrict__ in, float2* __restrict__ out) {
    __shared__ float tile[32][33];
    const int bx = blockIdx.x * 32, by = blockIdx.y * 32;
    const int tx = threadIdx.x, ty = threadIdx.y;
#pragma unroll
    for (int j = 0; j < 32; j += 8)
        tile[ty + j][tx] = in[(size_t)(by + ty + j) * 1024 + bx + tx];
    __syncthreads();
#pragma unroll
    for (int j = 0; j < 32; j += 8) {
        const int r = bx + ty + j;
        float v = tile[tx][ty + j];
        v = (r & 1) ? -v : v;
        out[(size_t)r * 1024 + by + tx] = make_float2(v, 0.0f);
    }
}

// inverse output: imf = (-1)^n * (1/N) * Re(.), transposed store
__global__ __launch_bounds__(256)
void k_tr_out(const float2* __restrict__ in, float* __restrict__ out) {
    __shared__ float2 tile[32][33];
    const size_t zo = (size_t)blockIdx.z * TN;
    const int bx = blockIdx.x * 32, by = blockIdx.y * 32;
    const int tx = threadIdx.x, ty = threadIdx.y;
#pragma unroll
    for (int j = 0; j < 32; j += 8)
        tile[ty + j][tx] = in[zo + (size_t)(by + ty + j) * 1024 + bx + tx];
    __syncthreads();
    const int c = by + tx;
    const float sgn = (c & 1) ? -FINV_T : FINV_T;
#pragma unroll
    for (int j = 0; j < 32; j += 8) {
        const int r = bx + ty + j;
        out[zo + (size_t)r * 1024 + c] = tile[tx][ty + j].x * sgn;
    }
}

// ---------------------------------------------------------------------------
extern "C" void kernel_launch(void* const* d_in, const int* in_sizes, int n_in,
                              void* d_out, int out_size, void* d_ws, size_t ws_size,
                              hipStream_t stream) {
    (void)in_sizes; (void)n_in; (void)out_size;
    const float* x      = (const float*)d_in[0];
    const float* omega0 = (const float*)d_in[1];
    float* outp = (float*)d_out;
    char* ws = (char*)d_ws;

    const size_t MB = (size_t)1 << 20;
    float2* fhat   = (float2*)(ws);                  // 8 MB (scrambled order)
    float2* lamOut = (float2*)(ws + 8 * MB);         // 8 MB
    float*  pbuf   = (float*)(ws + 16 * MB);         // 2 slots * 8*CNB (16 KB)
    unsigned* flags = (unsigned*)(ws + 16 * MB + 64 * 1024);   // CNB epochs
    float*  oom    = (float*)(ws + 16 * MB + 68 * 1024);       // 3 floats
    const bool batch3 = ws_size >= 66 * MB;
    float2* sA = (float2*)(ws + 17 * MB);            // 24 or 8 MB
    float2* sB = batch3 ? (float2*)(ws + 41 * MB)
                        : (float2*)(ws + 25 * MB);

    dim3 tb(32, 8);
    dim3 tg(32, 32);

    k_init0<<<1, CNB, 0, stream>>>(flags);

    // forward FFT of (-1)^n*x -> fhat in scrambled order (4 passes)
    k_tr_fwd_in<<<tg, tb, 0, stream>>>(x, sA);
    k_fft1024<<<1024, 256, 0, stream>>>(sA, sB, -1.0f, 1);
    k_tr_c2c<<<tg, tb, 0, stream>>>(sB, sA);
    k_fft1024<<<1024, 256, 0, stream>>>(sA, fhat, -1.0f, 0);

    // all 50 VMD iterations in one cooperative kernel, state in registers
    {
        void* kargs[] = {(void*)&fhat, (void*)&omega0, (void*)&lamOut,
                         (void*)&pbuf, (void*)&flags, (void*)&oom};
        hipLaunchCooperativeKernel((const void*)k_vmd_all,
                                   dim3(CNB), dim3(CNT), kargs, 0, stream);
    }

    // inverse FFTs of u_k (u fused into first pass), output (-1)^n*Re(.)/N
    if (batch3) {
        k_fftu<<<3072, 256, 0, stream>>>(fhat, lamOut, oom, sB, 0);
        k_tr_c2c<<<dim3(32, 32, 3), tb, 0, stream>>>(sB, sA);
        k_fft1024<<<3072, 256, 0, stream>>>(sA, sB, 1.0f, 0);
        k_tr_out<<<dim3(32, 32, 3), tb, 0, stream>>>(sB, outp);
    } else {
        for (int k = 0; k < 3; ++k) {
            k_fftu<<<1024, 256, 0, stream>>>(fhat, lamOut, oom, sB, k);
            k_tr_c2c<<<tg, tb, 0, stream>>>(sB, sA);
            k_fft1024<<<1024, 256, 0, stream>>>(sA, sB, 1.0f, 0);
            k_tr_out<<<tg, tb, 0, stream>>>(sB, outp + (size_t)k * TN);
        }
    }
}

// Round 6
// 453.217 us; speedup vs baseline: 3.9320x; 1.0733x over previous
//
#include <hip/hip_runtime.h>
#include <math.h>

// ---------------------------------------------------------------------------
// VMD, T = 2^20, K = 3.  u[k][t] = (f_hat[t] - lam[t]/2) * g_k(t), g_k real:
// u is never materialized.  fftshift folded into (-1)^n input modulation;
// ifftshift into (-1)^n output sign.
//
// Round-6: persistent register-resident cooperative kernel with a
// SINGLE-AGGREGATOR barrier.  Round 5 had all 256 blocks polling the flag
// array (read stream vs arrival stores on the same lines) and all 256 blocks
// redundantly reducing the same 8 KB of partials.  Now: only block 0 polls
// flags; block 0's wave 0 reduces the partials alone and publishes {omega,
// stop} + epoch word; other blocks poll ONE line with one lane (s_sleep
// backoff).  Ordering: relaxed agent stores -> __syncthreads (vmcnt drain) ->
// epoch/flag store (pattern validated rounds 4-5).
// Also: __builtin_amdgcn_rcpf for the iteration divisions, __sincosf (HW
// v_sin/v_cos) in the FFT kernels.
// ---------------------------------------------------------------------------

#define TN        (1 << 20)
#define CNB       256         // cooperative grid: blocks
#define CNT       1024        // cooperative block: threads
#define FALPHA    2000.0f
#define FTAU      1e-7f
#define FTOL      1e-6f
#define FEPS      1e-8f
#define FTWO_PI   6.28318530717958647692f
#define FINV_T    (1.0f / 1048576.0f)

__device__ __forceinline__ float2 cmulf(float2 a, float2 b) {
    return make_float2(a.x * b.x - a.y * b.y, a.x * b.y + a.y * b.x);
}
__device__ __forceinline__ float2 cisf(float a) {
    float s, c;
    __sincosf(a, &s, &c);     // HW v_sin/v_cos; |err| ~1e-6, fine vs margin
    return make_float2(c, s);
}

// g_k(fr) for K=3 with neighbor coupling (stale omega, like the reference)
__device__ __forceinline__ void g3f(float fr, float om0, float om1, float om2,
                                    float& g0, float& g1, float& g2) {
    const float tau2 = FTAU * FTAU;
    float d0 = fr - om0; d0 *= d0;
    float d1 = fr - om1; d1 *= d1;
    float d2 = fr - om2; d2 *= d2;
    g0 = __builtin_amdgcn_rcpf(1.0f + FALPHA * (d0 + d1 + tau2));
    g1 = __builtin_amdgcn_rcpf(1.0f + FALPHA * (d0 + d1 + d2 + tau2));
    g2 = __builtin_amdgcn_rcpf(1.0f + FALPHA * (d1 + d2 + tau2));
}

// one complex point, fully register-resident.
// lx,ly = lam_{n-1} (updated to lam_n); px,py = lam_{n-2} (updated to lam_{n-1})
__device__ __forceinline__ void vmd_pt(
    float fr, float fx, float fy,
    float& lx, float& ly, float& px, float& py, int check,
    float om0, float om1, float om2,
    float op0, float op1, float op2, float* acc) {
    float cr = fx - 0.5f * lx;
    float ci = fy - 0.5f * ly;
    float g0, g1, g2;
    g3f(fr, om0, om1, om2, g0, g1, g2);
    float m2 = cr * cr + ci * ci;
    float q0 = m2 * g0 * g0, q1 = m2 * g1 * g1, q2 = m2 * g2 * g2;
    acc[0] += q0; acc[1] += q1; acc[2] += q2;
    acc[3] += q0 * fr; acc[4] += q1 * fr; acc[5] += q2 * fr;
    if (check) {   // u_prev from lam_{n-2} (px,py) and om entering n-1
        float pr = fx - 0.5f * px;
        float pi = fy - 0.5f * py;
        float h0, h1, h2;
        g3f(fr, op0, op1, op2, h0, h1, h2);
        float ax, ay, s = 0.f;
        ax = cr * g0 - pr * h0; ay = ci * g0 - pi * h0; s += ax * ax + ay * ay;
        ax = cr * g1 - pr * h1; ay = ci * g1 - pi * h1; s += ax * ax + ay * ay;
        ax = cr * g2 - pr * h2; ay = ci * g2 - pi * h2; s += ax * ax + ay * ay;
        acc[6] += s;
        acc[7] += (pr * pr + pi * pi) * (h0 * h0 + h1 * h1 + h2 * h2);
    }
    float gs = g0 + g1 + g2;
    px = lx; py = ly;                       // lam_prev <- lam_{n-1}
    lx = lx + FTAU * (cr * gs - fx);        // lam_n
    ly = ly + FTAU * (ci * gs - fy);
}

// zero flags + epoch (ws is re-poisoned to 0xAA before every timed launch)
__global__ __launch_bounds__(CNB)
void k_init0(unsigned* __restrict__ flags, unsigned* __restrict__ epoch) {
    flags[threadIdx.x] = 0u;
    if (threadIdx.x == 0) *epoch = 0u;
}

// ---------------------------------------------------------------------------
// the whole 50-iteration VMD loop: single-aggregator epoch barrier
// ---------------------------------------------------------------------------
__global__ __launch_bounds__(CNT)
void k_vmd_all(const float2* __restrict__ fhat,
               const float* __restrict__ omega0,
               float2* __restrict__ lamOut,
               float* __restrict__ pbuf,      // 2 slots * 8*CNB floats
               unsigned* __restrict__ flags,  // CNB arrival epochs
               float* __restrict__ pkt,       // {om0,om1,om2,stop}
               unsigned* __restrict__ epoch,  // published-iteration word
               float* __restrict__ oom) {
    const int tid  = threadIdx.x;
    const int bid  = blockIdx.x;
    const int gtid = bid * CNT + tid;        // 0 .. 262143
    const int lane = tid & 63;
    const int wid  = tid >> 6;               // 0..15

    // --- load this thread's 4 complex points of f_hat into registers ---
    const float4* __restrict__ f4 = (const float4*)fhat;
    float4 f0 = f4[gtid * 2];
    float4 f1 = f4[gtid * 2 + 1];
    // true (fftshifted) frequencies of the 4 scrambled points
    float fr[4];
#pragma unroll
    for (int j = 0; j < 4; ++j) {
        const int q = gtid * 4 + j;
        const int t = ((q & 1023) << 10) | (q >> 10);
        fr[j] = (float)t * FINV_T - 0.5f;
    }
    float4 lmA = make_float4(0.f, 0.f, 0.f, 0.f);  // lam_{n-1} (pts 0,1)
    float4 lmB = make_float4(0.f, 0.f, 0.f, 0.f);  // lam_{n-1} (pts 2,3)
    float4 lpA = make_float4(0.f, 0.f, 0.f, 0.f);  // lam_{n-2}
    float4 lpB = make_float4(0.f, 0.f, 0.f, 0.f);

    float om0 = 0.5f * omega0[0];
    float om1 = 0.5f * omega0[1];
    float om2 = 0.5f * omega0[2];
    float op0 = om0, op1 = om1, op2 = om2;   // om entering n-1

    __shared__ float wred[16][8];
    __shared__ float bcast[4];

    for (int n = 0; n < 50; ++n) {
        if (n > 0) {
            if (bid == 0) {
                // ---- aggregator: wait all arrivals, reduce, publish ----
                if (wid == 0) {
                    const unsigned tgt = (unsigned)n;
                    for (;;) {
                        unsigned a = __hip_atomic_load(&flags[lane],
                                       __ATOMIC_RELAXED, __HIP_MEMORY_SCOPE_AGENT);
                        unsigned b = __hip_atomic_load(&flags[lane + 64],
                                       __ATOMIC_RELAXED, __HIP_MEMORY_SCOPE_AGENT);
                        unsigned c = __hip_atomic_load(&flags[lane + 128],
                                       __ATOMIC_RELAXED, __HIP_MEMORY_SCOPE_AGENT);
                        unsigned d = __hip_atomic_load(&flags[lane + 192],
                                       __ATOMIC_RELAXED, __HIP_MEMORY_SCOPE_AGENT);
                        unsigned m = min(min(a, b), min(c, d));
                        if (__all(m >= tgt)) break;
                        __builtin_amdgcn_s_sleep(1);
                    }
                    // partials of iter n-1, fixed-order reduce in wave 0
                    const float* __restrict__ pp =
                        pbuf + ((n - 1) & 1) * (8 * CNB);
                    double d[8];
#pragma unroll
                    for (int v = 0; v < 8; ++v) {
                        double s = 0.0;
#pragma unroll
                        for (int g = 0; g < 4; ++g)
                            s += (double)__hip_atomic_load(
                                     &pp[v * CNB + lane + 64 * g],
                                     __ATOMIC_RELAXED, __HIP_MEMORY_SCOPE_AGENT);
                        d[v] = s;
                    }
#pragma unroll
                    for (int off = 32; off > 0; off >>= 1) {
#pragma unroll
                        for (int v = 0; v < 8; ++v)
                            d[v] += __shfl_down(d[v], off);
                    }
                    if (lane == 0) {
                        const float n0 = (float)(d[3] / (d[0] + (double)FEPS));
                        const float n1 = (float)(d[4] / (d[1] + (double)FEPS));
                        const float n2 = (float)(d[5] / (d[2] + (double)FEPS));
                        float stop = 0.f;
                        if ((n - 1) % 10 == 0 && (n - 1) > 0) {
                            const double ud = d[6] / (d[7] + (double)FEPS);
                            const float od = (fabsf(n0 - n2) + fabsf(n1 - n0) +
                                              fabsf(n2 - n1)) * (1.0f / 3.0f);
                            if (ud < (double)FTOL && od < FTOL) stop = 1.f;
                        }
                        bcast[0] = n0; bcast[1] = n1; bcast[2] = n2;
                        bcast[3] = stop;
                        __hip_atomic_store(&pkt[0], n0, __ATOMIC_RELAXED,
                                           __HIP_MEMORY_SCOPE_AGENT);
                        __hip_atomic_store(&pkt[1], n1, __ATOMIC_RELAXED,
                                           __HIP_MEMORY_SCOPE_AGENT);
                        __hip_atomic_store(&pkt[2], n2, __ATOMIC_RELAXED,
                                           __HIP_MEMORY_SCOPE_AGENT);
                        __hip_atomic_store(&pkt[3], stop, __ATOMIC_RELAXED,
                                           __HIP_MEMORY_SCOPE_AGENT);
                    }
                }
                __syncthreads();   // drains vmcnt: pkt data at LLC before epoch
                if (tid == 0)
                    __hip_atomic_store(epoch, (unsigned)n, __ATOMIC_RELAXED,
                                       __HIP_MEMORY_SCOPE_AGENT);
            } else {
                // ---- consumer: poll the single epoch line, fetch packet ----
                if (tid == 0) {
                    while (__hip_atomic_load(epoch, __ATOMIC_RELAXED,
                                             __HIP_MEMORY_SCOPE_AGENT)
                           < (unsigned)n)
                        __builtin_amdgcn_s_sleep(1);
                    bcast[0] = __hip_atomic_load(&pkt[0], __ATOMIC_RELAXED,
                                                 __HIP_MEMORY_SCOPE_AGENT);
                    bcast[1] = __hip_atomic_load(&pkt[1], __ATOMIC_RELAXED,
                                                 __HIP_MEMORY_SCOPE_AGENT);
                    bcast[2] = __hip_atomic_load(&pkt[2], __ATOMIC_RELAXED,
                                                 __HIP_MEMORY_SCOPE_AGENT);
                    bcast[3] = __hip_atomic_load(&pkt[3], __ATOMIC_RELAXED,
                                                 __HIP_MEMORY_SCOPE_AGENT);
                }
                __syncthreads();
            }
            if (bcast[3] != 0.f) break;      // identical decision everywhere
            op0 = om0; op1 = om1; op2 = om2;
            om0 = bcast[0]; om1 = bcast[1]; om2 = bcast[2];
        }

        const int check = (n > 0 && (n % 10) == 0) ? 1 : 0;
        float acc[8];
#pragma unroll
        for (int v = 0; v < 8; ++v) acc[v] = 0.f;

        vmd_pt(fr[0], f0.x, f0.y, lmA.x, lmA.y, lpA.x, lpA.y, check,
               om0, om1, om2, op0, op1, op2, acc);
        vmd_pt(fr[1], f0.z, f0.w, lmA.z, lmA.w, lpA.z, lpA.w, check,
               om0, om1, om2, op0, op1, op2, acc);
        vmd_pt(fr[2], f1.x, f1.y, lmB.x, lmB.y, lpB.x, lpB.y, check,
               om0, om1, om2, op0, op1, op2, acc);
        vmd_pt(fr[3], f1.z, f1.w, lmB.z, lmB.w, lpB.z, lpB.w, check,
               om0, om1, om2, op0, op1, op2, acc);

        // ---- block reduction (fixed tree -> deterministic) ----
#pragma unroll
        for (int off = 32; off > 0; off >>= 1) {
#pragma unroll
            for (int v = 0; v < 8; ++v) acc[v] += __shfl_down(acc[v], off);
        }
        if (lane == 0) {
#pragma unroll
            for (int v = 0; v < 8; ++v) wred[wid][v] = acc[v];
        }
        __syncthreads();
        if (tid < 8) {
            float s = 0.f;
#pragma unroll
            for (int w = 0; w < 16; ++w) s += wred[w][tid];
            __hip_atomic_store(&pbuf[(n & 1) * (8 * CNB) + tid * CNB + bid], s,
                               __ATOMIC_RELAXED, __HIP_MEMORY_SCOPE_AGENT);
        }
        __syncthreads();   // drains vmcnt: partial stores at LLC before flag
        if (tid == 0)
            __hip_atomic_store(&flags[bid], (unsigned)(n + 1),
                               __ATOMIC_RELAXED, __HIP_MEMORY_SCOPE_AGENT);
    }

    // ---- output state: lam_prev + omega that generated the last u ----
    float4* __restrict__ lo4 = (float4*)lamOut;
    lo4[gtid * 2]     = lpA;
    lo4[gtid * 2 + 1] = lpB;
    if (gtid == 0) { oom[0] = om0; oom[1] = om1; oom[2] = om2; }
}

// ---------------------------------------------------------------------------
// 1024-point Stockham radix-4 stages in LDS (caller loads bufA, then syncs)
// ---------------------------------------------------------------------------
__device__ __forceinline__ float2* fft1024_stages(float2* bufA, float2* bufB,
                                                  int t, float dir) {
    float2* src = bufA;
    float2* dst = bufB;
    int Ns = 1;
#pragma unroll
    for (int s = 0; s < 5; ++s) {
        const int jm = t & (Ns - 1);
        float2 v0 = src[t], v1 = src[t + 256], v2 = src[t + 512], v3 = src[t + 768];
        const float a = dir * (FTWO_PI * 0.25f) * ((float)jm / (float)Ns);
        float2 w1 = cisf(a);
        float2 w2 = cmulf(w1, w1);
        float2 w3 = cmulf(w2, w1);
        v1 = cmulf(v1, w1); v2 = cmulf(v2, w2); v3 = cmulf(v3, w3);
        float2 s0 = make_float2(v0.x + v2.x, v0.y + v2.y);
        float2 s1 = make_float2(v0.x - v2.x, v0.y - v2.y);
        float2 s2 = make_float2(v1.x + v3.x, v1.y + v3.y);
        float2 s3 = make_float2(v1.x - v3.x, v1.y - v3.y);
        float2 s3i = make_float2(-dir * s3.y, dir * s3.x);  // dir*i * s3
        const int base = ((t - jm) << 2) + jm;
        dst[base]          = make_float2(s0.x + s2.x, s0.y + s2.y);
        dst[base + Ns]     = make_float2(s1.x + s3i.x, s1.y + s3i.y);
        dst[base + 2 * Ns] = make_float2(s0.x - s2.x, s0.y - s2.y);
        dst[base + 3 * Ns] = make_float2(s1.x - s3i.x, s1.y - s3i.y);
        __syncthreads();
        float2* tmp = src; src = dst; dst = tmp;
        Ns <<= 2;
    }
    return src;
}

// generic row FFT: dir=-1 fwd / +1 inv; do_tw: * e^{dir*2pi*i*row*col/2^20}
__global__ __launch_bounds__(256)
void k_fft1024(const float2* __restrict__ in, float2* __restrict__ out,
               float dir, int do_tw) {
    __shared__ float2 bufA[1024];
    __shared__ float2 bufB[1024];
    const int row  = blockIdx.x;
    const int rowm = row & 1023;
    const float2* __restrict__ rin  = in  + (size_t)row * 1024;
    float2* __restrict__ rout = out + (size_t)row * 1024;
    const int t = threadIdx.x;
#pragma unroll
    for (int r = 0; r < 4; ++r) bufA[t + 256 * r] = rin[t + 256 * r];
    __syncthreads();
    float2* src = fft1024_stages(bufA, bufB, t, dir);
#pragma unroll
    for (int r = 0; r < 4; ++r) {
        const int c = t + 256 * r;
        float2 xv = src[c];
        if (do_tw) {
            const unsigned p = ((unsigned)rowm * (unsigned)c) & 1048575u;
            xv = cmulf(xv, cisf(dir * (FTWO_PI * FINV_T) * (float)p));
        }
        rout[c] = xv;
    }
}

// first inverse-FFT pass with u-compute fused into the load stage.
// Scrambled row `row` of fhat/lam IS the k2-row the inverse six-step needs.
__global__ __launch_bounds__(256)
void k_fftu(const float2* __restrict__ fhat, const float2* __restrict__ lam,
            const float* __restrict__ oom,
            float2* __restrict__ out, int kbase) {
    __shared__ float2 bufA[1024];
    __shared__ float2 bufB[1024];
    const int row = blockIdx.x & 1023;
    const int z   = blockIdx.x >> 10;
    const int kk  = kbase + z;
    const float om0 = oom[0], om1 = oom[1], om2 = oom[2];
    const float2* __restrict__ frow = fhat + (size_t)row * 1024;
    const float2* __restrict__ lrow = lam  + (size_t)row * 1024;
    const int t = threadIdx.x;
#pragma unroll
    for (int r = 0; r < 4; ++r) {
        const int c = t + 256 * r;
        const float2 f  = frow[c];
        const float2 la = lrow[c];
        const float cr = f.x - 0.5f * la.x;
        const float ci = f.y - 0.5f * la.y;
        const float fr = (float)((c << 10) | row) * FINV_T - 0.5f;
        float g0, g1, g2;
        g3f(fr, om0, om1, om2, g0, g1, g2);
        const float g = (kk == 0) ? g0 : ((kk == 1) ? g1 : g2);
        bufA[c] = make_float2(cr * g, ci * g);
    }
    __syncthreads();
    float2* src = fft1024_stages(bufA, bufB, t, 1.0f);
    float2* __restrict__ rout = out + (size_t)z * TN + (size_t)row * 1024;
#pragma unroll
    for (int r = 0; r < 4; ++r) {
        const int c = t + 256 * r;
        const unsigned p = ((unsigned)row * (unsigned)c) & 1048575u;
        rout[c] = cmulf(src[c], cisf((FTWO_PI * FINV_T) * (float)p));
    }
}

// ---------------------------------------------------------------------------
// transposes (32x32 LDS tiles, block (32,8)); grid z = batch
// ---------------------------------------------------------------------------
__global__ __launch_bounds__(256)
void k_tr_c2c(const float2* __restrict__ in, float2* __restrict__ out) {
    __shared__ float2 tile[32][33];
    const size_t zo = (size_t)blockIdx.z * TN;
    const int bx = blockIdx.x * 32, by = blockIdx.y * 32;
    const int tx = threadIdx.x, ty = threadIdx.y;
#pragma unroll
    for (int j = 0; j < 32; j += 8)
        tile[ty + j][tx] = in[zo + (size_t)(by + ty + j) * 1024 + bx + tx];
    __syncthreads();
#pragma unroll
    for (int j = 0; j < 32; j += 8)
        out[zo + (size_t)(bx + ty + j) * 1024 + by + tx] = tile[tx][ty + j];
}

// forward input: y = (-1)^n * x, transposed, real -> complex
__global__ __launch_bounds__(256)
void k_tr_fwd_in(const float* __restrict__ in, float2* __restrict__ out) {
    __shared__ float tile[32][33];
    const int bx = blockIdx.x * 32, by = blockIdx.y * 32;
    const int tx = threadIdx.x, ty = threadIdx.y;
#pragma unroll
    for (int j = 0; j < 32; j += 8)
        tile[ty + j][tx] = in[(size_t)(by + ty + j) * 1024 + bx + tx];
    __syncthreads();
#pragma unroll
    for (int j = 0; j < 32; j += 8) {
        const int r = bx + ty + j;
        float v = tile[tx][ty + j];
        v = (r & 1) ? -v : v;
        out[(size_t)r * 1024 + by + tx] = make_float2(v, 0.0f);
    }
}

// inverse output: imf = (-1)^n * (1/N) * Re(.), transposed store
__global__ __launch_bounds__(256)
void k_tr_out(const float2* __restrict__ in, float* __restrict__ out) {
    __shared__ float2 tile[32][33];
    const size_t zo = (size_t)blockIdx.z * TN;
    const int bx = blockIdx.x * 32, by = blockIdx.y * 32;
    const int tx = threadIdx.x, ty = threadIdx.y;
#pragma unroll
    for (int j = 0; j < 32; j += 8)
        tile[ty + j][tx] = in[zo + (size_t)(by + ty + j) * 1024 + bx + tx];
    __syncthreads();
    const int c = by + tx;
    const float sgn = (c & 1) ? -FINV_T : FINV_T;
#pragma unroll
    for (int j = 0; j < 32; j += 8) {
        const int r = bx + ty + j;
        out[zo + (size_t)r * 1024 + c] = tile[tx][ty + j].x * sgn;
    }
}

// ---------------------------------------------------------------------------
extern "C" void kernel_launch(void* const* d_in, const int* in_sizes, int n_in,
                              void* d_out, int out_size, void* d_ws, size_t ws_size,
                              hipStream_t stream) {
    (void)in_sizes; (void)n_in; (void)out_size;
    const float* x      = (const float*)d_in[0];
    const float* omega0 = (const float*)d_in[1];
    float* outp = (float*)d_out;
    char* ws = (char*)d_ws;

    const size_t MB = (size_t)1 << 20;
    float2* fhat   = (float2*)(ws);                  // 8 MB (scrambled order)
    float2* lamOut = (float2*)(ws + 8 * MB);         // 8 MB
    float*  pbuf   = (float*)(ws + 16 * MB);         // 2 slots * 8*CNB (16 KB)
    unsigned* flags = (unsigned*)(ws + 16 * MB + 64 * 1024);   // CNB arrivals
    float*  pkt    = (float*)(ws + 16 * MB + 68 * 1024);       // 4 floats
    unsigned* epoch = (unsigned*)(ws + 16 * MB + 68 * 1024 + 128);
    float*  oom    = (float*)(ws + 16 * MB + 72 * 1024);       // 3 floats
    const bool batch3 = ws_size >= 66 * MB;
    float2* sA = (float2*)(ws + 17 * MB);            // 24 or 8 MB
    float2* sB = batch3 ? (float2*)(ws + 41 * MB)
                        : (float2*)(ws + 25 * MB);

    dim3 tb(32, 8);
    dim3 tg(32, 32);

    k_init0<<<1, CNB, 0, stream>>>(flags, epoch);

    // forward FFT of (-1)^n*x -> fhat in scrambled order (4 passes)
    k_tr_fwd_in<<<tg, tb, 0, stream>>>(x, sA);
    k_fft1024<<<1024, 256, 0, stream>>>(sA, sB, -1.0f, 1);
    k_tr_c2c<<<tg, tb, 0, stream>>>(sB, sA);
    k_fft1024<<<1024, 256, 0, stream>>>(sA, fhat, -1.0f, 0);

    // all 50 VMD iterations in one cooperative kernel, state in registers
    {
        void* kargs[] = {(void*)&fhat, (void*)&omega0, (void*)&lamOut,
                         (void*)&pbuf, (void*)&flags, (void*)&pkt,
                         (void*)&epoch, (void*)&oom};
        hipLaunchCooperativeKernel((const void*)k_vmd_all,
                                   dim3(CNB), dim3(CNT), kargs, 0, stream);
    }

    // inverse FFTs of u_k (u fused into first pass), output (-1)^n*Re(.)/N
    if (batch3) {
        k_fftu<<<3072, 256, 0, stream>>>(fhat, lamOut, oom, sB, 0);
        k_tr_c2c<<<dim3(32, 32, 3), tb, 0, stream>>>(sB, sA);
        k_fft1024<<<3072, 256, 0, stream>>>(sA, sB, 1.0f, 0);
        k_tr_out<<<dim3(32, 32, 3), tb, 0, stream>>>(sB, outp);
    } else {
        for (int k = 0; k < 3; ++k) {
            k_fftu<<<1024, 256, 0, stream>>>(fhat, lamOut, oom, sB, k);
            k_tr_c2c<<<tg, tb, 0, stream>>>(sB, sA);
            k_fft1024<<<1024, 256, 0, stream>>>(sA, sB, 1.0f, 0);
            k_tr_out<<<tg, tb, 0, stream>>>(sB, outp + (size_t)k * TN);
        }
    }
}

// Round 7
// 409.593 us; speedup vs baseline: 4.3508x; 1.1065x over previous
//
#include <hip/hip_runtime.h>
#include <math.h>

// ---------------------------------------------------------------------------
// VMD, T = 2^20, K = 3.  u[k][t] = (f_hat[t] - lam[t]/2) * g_k(t), g_k real:
// u is never materialized.  fftshift folded into (-1)^n input modulation;
// ifftshift into (-1)^n output sign.
//
// Round-7: ONE-HOP exchange.  Each block's 8 partial sums are stored as
// self-validating u64 records {epoch<<32 | float_bits} (relaxed agent-scope
// atomics, LLC-coherent).  Data and arrival flag are the same word, so the
// round-6 chain (partials -> drain -> flag -> agg poll -> agg fetch -> reduce
// -> pkt -> drain -> epoch -> consumer poll -> pkt fetch: ~6 LLC round trips,
// ~5us/iter) collapses to: store records -> every block's wave 0 polls all
// 256x8 records (coalesced, accumulate-while-check) -> local fixed-order
// reduce (bitwise-identical omega everywhere) -> LDS bcast.  ~1us/iter.
// Exact-match epoch==n-1 also makes 0xAA ws-poison harmless: no init kernel.
// Slot parity (n&1) + the inductive consumption argument => no overwrite
// hazard (a slot is rewritten at n+2 only after all blocks consumed n).
// ---------------------------------------------------------------------------

#define TN        (1 << 20)
#define CNB       256         // cooperative grid: blocks
#define CNT       1024        // cooperative block: threads
#define FALPHA    2000.0f
#define FTAU      1e-7f
#define FTOL      1e-6f
#define FEPS      1e-8f
#define FTWO_PI   6.28318530717958647692f
#define FINV_T    (1.0f / 1048576.0f)

typedef unsigned long long ull;

__device__ __forceinline__ float2 cmulf(float2 a, float2 b) {
    return make_float2(a.x * b.x - a.y * b.y, a.x * b.y + a.y * b.x);
}
__device__ __forceinline__ float2 cisf(float a) {
    float s, c;
    __sincosf(a, &s, &c);     // HW v_sin/v_cos; |err| ~1e-6, fine vs margin
    return make_float2(c, s);
}

// g_k(fr) for K=3 with neighbor coupling (stale omega, like the reference)
__device__ __forceinline__ void g3f(float fr, float om0, float om1, float om2,
                                    float& g0, float& g1, float& g2) {
    const float tau2 = FTAU * FTAU;
    float d0 = fr - om0; d0 *= d0;
    float d1 = fr - om1; d1 *= d1;
    float d2 = fr - om2; d2 *= d2;
    g0 = __builtin_amdgcn_rcpf(1.0f + FALPHA * (d0 + d1 + tau2));
    g1 = __builtin_amdgcn_rcpf(1.0f + FALPHA * (d0 + d1 + d2 + tau2));
    g2 = __builtin_amdgcn_rcpf(1.0f + FALPHA * (d1 + d2 + tau2));
}

// one complex point, fully register-resident.
// lx,ly = lam_{n-1} (updated to lam_n); px,py = lam_{n-2} (updated to lam_{n-1})
__device__ __forceinline__ void vmd_pt(
    float fr, float fx, float fy,
    float& lx, float& ly, float& px, float& py, int check,
    float om0, float om1, float om2,
    float op0, float op1, float op2, float* acc) {
    float cr = fx - 0.5f * lx;
    float ci = fy - 0.5f * ly;
    float g0, g1, g2;
    g3f(fr, om0, om1, om2, g0, g1, g2);
    float m2 = cr * cr + ci * ci;
    float q0 = m2 * g0 * g0, q1 = m2 * g1 * g1, q2 = m2 * g2 * g2;
    acc[0] += q0; acc[1] += q1; acc[2] += q2;
    acc[3] += q0 * fr; acc[4] += q1 * fr; acc[5] += q2 * fr;
    if (check) {   // u_prev from lam_{n-2} (px,py) and om entering n-1
        float pr = fx - 0.5f * px;
        float pi = fy - 0.5f * py;
        float h0, h1, h2;
        g3f(fr, op0, op1, op2, h0, h1, h2);
        float ax, ay, s = 0.f;
        ax = cr * g0 - pr * h0; ay = ci * g0 - pi * h0; s += ax * ax + ay * ay;
        ax = cr * g1 - pr * h1; ay = ci * g1 - pi * h1; s += ax * ax + ay * ay;
        ax = cr * g2 - pr * h2; ay = ci * g2 - pi * h2; s += ax * ax + ay * ay;
        acc[6] += s;
        acc[7] += (pr * pr + pi * pi) * (h0 * h0 + h1 * h1 + h2 * h2);
    }
    float gs = g0 + g1 + g2;
    px = lx; py = ly;                       // lam_prev <- lam_{n-1}
    lx = lx + FTAU * (cr * gs - fx);        // lam_n
    ly = ly + FTAU * (ci * gs - fy);
}

// ---------------------------------------------------------------------------
// the whole 50-iteration VMD loop: one-hop self-validating-record exchange
// ---------------------------------------------------------------------------
__global__ __launch_bounds__(CNT)
void k_vmd_all(const float2* __restrict__ fhat,
               const float* __restrict__ omega0,
               float2* __restrict__ lamOut,
               ull* __restrict__ rec,         // 2 slots * 8*CNB u64 records
               float* __restrict__ oom) {
    const int tid  = threadIdx.x;
    const int bid  = blockIdx.x;
    const int gtid = bid * CNT + tid;        // 0 .. 262143
    const int lane = tid & 63;
    const int wid  = tid >> 6;               // 0..15

    // --- load this thread's 4 complex points of f_hat into registers ---
    const float4* __restrict__ f4 = (const float4*)fhat;
    float4 f0 = f4[gtid * 2];
    float4 f1 = f4[gtid * 2 + 1];
    // true (fftshifted) frequencies of the 4 scrambled points
    float fr[4];
#pragma unroll
    for (int j = 0; j < 4; ++j) {
        const int q = gtid * 4 + j;
        const int t = ((q & 1023) << 10) | (q >> 10);
        fr[j] = (float)t * FINV_T - 0.5f;
    }
    float4 lmA = make_float4(0.f, 0.f, 0.f, 0.f);  // lam_{n-1} (pts 0,1)
    float4 lmB = make_float4(0.f, 0.f, 0.f, 0.f);  // lam_{n-1} (pts 2,3)
    float4 lpA = make_float4(0.f, 0.f, 0.f, 0.f);  // lam_{n-2}
    float4 lpB = make_float4(0.f, 0.f, 0.f, 0.f);

    float om0 = 0.5f * omega0[0];
    float om1 = 0.5f * omega0[1];
    float om2 = 0.5f * omega0[2];
    float op0 = om0, op1 = om1, op2 = om2;   // om entering n-1

    __shared__ float wred[16][8];
    __shared__ float bcast[4];

    for (int n = 0; n < 50; ++n) {
        if (n > 0) {
            // ---- one-hop: poll+fetch+reduce records of iteration n-1 ----
            if (wid == 0) {
                const ull* __restrict__ rp = rec + ((n - 1) & 1) * (8 * CNB);
                const unsigned want = (unsigned)(n - 1);
                double d[8];
                for (;;) {
                    unsigned bad = 0;
#pragma unroll
                    for (int v = 0; v < 8; ++v) d[v] = 0.0;
#pragma unroll
                    for (int v = 0; v < 8; ++v) {
#pragma unroll
                        for (int g = 0; g < 4; ++g) {
                            ull w = __hip_atomic_load(
                                &rp[v * CNB + lane + 64 * g],
                                __ATOMIC_RELAXED, __HIP_MEMORY_SCOPE_AGENT);
                            bad |= (unsigned)(w >> 32) ^ want;
                            d[v] += (double)__uint_as_float((unsigned)w);
                        }
                    }
                    if (__all(bad == 0)) break;
                    __builtin_amdgcn_s_sleep(1);
                }
                // fixed shuffle tree (identical order in every block)
#pragma unroll
                for (int off = 32; off > 0; off >>= 1) {
#pragma unroll
                    for (int v = 0; v < 8; ++v) d[v] += __shfl_down(d[v], off);
                }
                if (lane == 0) {
                    const float n0 = (float)(d[3] / (d[0] + (double)FEPS));
                    const float n1 = (float)(d[4] / (d[1] + (double)FEPS));
                    const float n2 = (float)(d[5] / (d[2] + (double)FEPS));
                    float stop = 0.f;
                    if ((n - 1) % 10 == 0 && (n - 1) > 0) {  // conv eval n-1
                        const double ud = d[6] / (d[7] + (double)FEPS);
                        const float od = (fabsf(n0 - n2) + fabsf(n1 - n0) +
                                          fabsf(n2 - n1)) * (1.0f / 3.0f);
                        if (ud < (double)FTOL && od < FTOL) stop = 1.f;
                    }
                    bcast[0] = n0; bcast[1] = n1; bcast[2] = n2;
                    bcast[3] = stop;
                }
            }
            __syncthreads();
            if (bcast[3] != 0.f) break;      // identical decision everywhere
            op0 = om0; op1 = om1; op2 = om2;
            om0 = bcast[0]; om1 = bcast[1]; om2 = bcast[2];
        }

        const int check = (n > 0 && (n % 10) == 0) ? 1 : 0;
        float acc[8];
#pragma unroll
        for (int v = 0; v < 8; ++v) acc[v] = 0.f;

        vmd_pt(fr[0], f0.x, f0.y, lmA.x, lmA.y, lpA.x, lpA.y, check,
               om0, om1, om2, op0, op1, op2, acc);
        vmd_pt(fr[1], f0.z, f0.w, lmA.z, lmA.w, lpA.z, lpA.w, check,
               om0, om1, om2, op0, op1, op2, acc);
        vmd_pt(fr[2], f1.x, f1.y, lmB.x, lmB.y, lpB.x, lpB.y, check,
               om0, om1, om2, op0, op1, op2, acc);
        vmd_pt(fr[3], f1.z, f1.w, lmB.z, lmB.w, lpB.z, lpB.w, check,
               om0, om1, om2, op0, op1, op2, acc);

        // ---- block reduction (fixed tree -> deterministic) ----
#pragma unroll
        for (int off = 32; off > 0; off >>= 1) {
#pragma unroll
            for (int v = 0; v < 8; ++v) acc[v] += __shfl_down(acc[v], off);
        }
        if (lane == 0) {
#pragma unroll
            for (int v = 0; v < 8; ++v) wred[wid][v] = acc[v];
        }
        __syncthreads();
        // ---- publish 8 self-validating records; no ordering needed:
        //      epoch and payload travel in the same atomic word ----
        if (tid < 8) {
            float s = 0.f;
#pragma unroll
            for (int w = 0; w < 16; ++w) s += wred[w][tid];
            const ull pk = ((ull)(unsigned)n << 32) | (ull)__float_as_uint(s);
            __hip_atomic_store(&rec[(n & 1) * (8 * CNB) + tid * CNB + bid], pk,
                               __ATOMIC_RELAXED, __HIP_MEMORY_SCOPE_AGENT);
        }
    }

    // ---- output state: lam_prev + omega that generated the last u ----
    float4* __restrict__ lo4 = (float4*)lamOut;
    lo4[gtid * 2]     = lpA;
    lo4[gtid * 2 + 1] = lpB;
    if (gtid == 0) { oom[0] = om0; oom[1] = om1; oom[2] = om2; }
}

// ---------------------------------------------------------------------------
// 1024-point Stockham radix-4 stages in LDS (caller loads bufA, then syncs)
// ---------------------------------------------------------------------------
__device__ __forceinline__ float2* fft1024_stages(float2* bufA, float2* bufB,
                                                  int t, float dir) {
    float2* src = bufA;
    float2* dst = bufB;
    int Ns = 1;
#pragma unroll
    for (int s = 0; s < 5; ++s) {
        const int jm = t & (Ns - 1);
        float2 v0 = src[t], v1 = src[t + 256], v2 = src[t + 512], v3 = src[t + 768];
        const float a = dir * (FTWO_PI * 0.25f) * ((float)jm / (float)Ns);
        float2 w1 = cisf(a);
        float2 w2 = cmulf(w1, w1);
        float2 w3 = cmulf(w2, w1);
        v1 = cmulf(v1, w1); v2 = cmulf(v2, w2); v3 = cmulf(v3, w3);
        float2 s0 = make_float2(v0.x + v2.x, v0.y + v2.y);
        float2 s1 = make_float2(v0.x - v2.x, v0.y - v2.y);
        float2 s2 = make_float2(v1.x + v3.x, v1.y + v3.y);
        float2 s3 = make_float2(v1.x - v3.x, v1.y - v3.y);
        float2 s3i = make_float2(-dir * s3.y, dir * s3.x);  // dir*i * s3
        const int base = ((t - jm) << 2) + jm;
        dst[base]          = make_float2(s0.x + s2.x, s0.y + s2.y);
        dst[base + Ns]     = make_float2(s1.x + s3i.x, s1.y + s3i.y);
        dst[base + 2 * Ns] = make_float2(s0.x - s2.x, s0.y - s2.y);
        dst[base + 3 * Ns] = make_float2(s1.x - s3i.x, s1.y - s3i.y);
        __syncthreads();
        float2* tmp = src; src = dst; dst = tmp;
        Ns <<= 2;
    }
    return src;
}

// generic row FFT: dir=-1 fwd / +1 inv; do_tw: * e^{dir*2pi*i*row*col/2^20}
__global__ __launch_bounds__(256)
void k_fft1024(const float2* __restrict__ in, float2* __restrict__ out,
               float dir, int do_tw) {
    __shared__ float2 bufA[1024];
    __shared__ float2 bufB[1024];
    const int row  = blockIdx.x;
    const int rowm = row & 1023;
    const float2* __restrict__ rin  = in  + (size_t)row * 1024;
    float2* __restrict__ rout = out + (size_t)row * 1024;
    const int t = threadIdx.x;
#pragma unroll
    for (int r = 0; r < 4; ++r) bufA[t + 256 * r] = rin[t + 256 * r];
    __syncthreads();
    float2* src = fft1024_stages(bufA, bufB, t, dir);
#pragma unroll
    for (int r = 0; r < 4; ++r) {
        const int c = t + 256 * r;
        float2 xv = src[c];
        if (do_tw) {
            const unsigned p = ((unsigned)rowm * (unsigned)c) & 1048575u;
            xv = cmulf(xv, cisf(dir * (FTWO_PI * FINV_T) * (float)p));
        }
        rout[c] = xv;
    }
}

// first inverse-FFT pass with u-compute fused into the load stage.
// Scrambled row `row` of fhat/lam IS the k2-row the inverse six-step needs.
__global__ __launch_bounds__(256)
void k_fftu(const float2* __restrict__ fhat, const float2* __restrict__ lam,
            const float* __restrict__ oom,
            float2* __restrict__ out, int kbase) {
    __shared__ float2 bufA[1024];
    __shared__ float2 bufB[1024];
    const int row = blockIdx.x & 1023;
    const int z   = blockIdx.x >> 10;
    const int kk  = kbase + z;
    const float om0 = oom[0], om1 = oom[1], om2 = oom[2];
    const float2* __restrict__ frow = fhat + (size_t)row * 1024;
    const float2* __restrict__ lrow = lam  + (size_t)row * 1024;
    const int t = threadIdx.x;
#pragma unroll
    for (int r = 0; r < 4; ++r) {
        const int c = t + 256 * r;
        const float2 f  = frow[c];
        const float2 la = lrow[c];
        const float cr = f.x - 0.5f * la.x;
        const float ci = f.y - 0.5f * la.y;
        const float fr = (float)((c << 10) | row) * FINV_T - 0.5f;
        float g0, g1, g2;
        g3f(fr, om0, om1, om2, g0, g1, g2);
        const float g = (kk == 0) ? g0 : ((kk == 1) ? g1 : g2);
        bufA[c] = make_float2(cr * g, ci * g);
    }
    __syncthreads();
    float2* src = fft1024_stages(bufA, bufB, t, 1.0f);
    float2* __restrict__ rout = out + (size_t)z * TN + (size_t)row * 1024;
#pragma unroll
    for (int r = 0; r < 4; ++r) {
        const int c = t + 256 * r;
        const unsigned p = ((unsigned)row * (unsigned)c) & 1048575u;
        rout[c] = cmulf(src[c], cisf((FTWO_PI * FINV_T) * (float)p));
    }
}

// ---------------------------------------------------------------------------
// transposes (32x32 LDS tiles, block (32,8)); grid z = batch
// ---------------------------------------------------------------------------
__global__ __launch_bounds__(256)
void k_tr_c2c(const float2* __restrict__ in, float2* __restrict__ out) {
    __shared__ float2 tile[32][33];
    const size_t zo = (size_t)blockIdx.z * TN;
    const int bx = blockIdx.x * 32, by = blockIdx.y * 32;
    const int tx = threadIdx.x, ty = threadIdx.y;
#pragma unroll
    for (int j = 0; j < 32; j += 8)
        tile[ty + j][tx] = in[zo + (size_t)(by + ty + j) * 1024 + bx + tx];
    __syncthreads();
#pragma unroll
    for (int j = 0; j < 32; j += 8)
        out[zo + (size_t)(bx + ty + j) * 1024 + by + tx] = tile[tx][ty + j];
}

// forward input: y = (-1)^n * x, transposed, real -> complex
__global__ __launch_bounds__(256)
void k_tr_fwd_in(const float* __restrict__ in, float2* __restrict__ out) {
    __shared__ float tile[32][33];
    const int bx = blockIdx.x * 32, by = blockIdx.y * 32;
    const int tx = threadIdx.x, ty = threadIdx.y;
#pragma unroll
    for (int j = 0; j < 32; j += 8)
        tile[ty + j][tx] = in[(size_t)(by + ty + j) * 1024 + bx + tx];
    __syncthreads();
#pragma unroll
    for (int j = 0; j < 32; j += 8) {
        const int r = bx + ty + j;
        float v = tile[tx][ty + j];
        v = (r & 1) ? -v : v;
        out[(size_t)r * 1024 + by + tx] = make_float2(v, 0.0f);
    }
}

// inverse output: imf = (-1)^n * (1/N) * Re(.), transposed store
__global__ __launch_bounds__(256)
void k_tr_out(const float2* __restrict__ in, float* __restrict__ out) {
    __shared__ float2 tile[32][33];
    const size_t zo = (size_t)blockIdx.z * TN;
    const int bx = blockIdx.x * 32, by = blockIdx.y * 32;
    const int tx = threadIdx.x, ty = threadIdx.y;
#pragma unroll
    for (int j = 0; j < 32; j += 8)
        tile[ty + j][tx] = in[zo + (size_t)(by + ty + j) * 1024 + bx + tx];
    __syncthreads();
    const int c = by + tx;
    const float sgn = (c & 1) ? -FINV_T : FINV_T;
#pragma unroll
    for (int j = 0; j < 32; j += 8) {
        const int r = bx + ty + j;
        out[zo + (size_t)r * 1024 + c] = tile[tx][ty + j].x * sgn;
    }
}

// ---------------------------------------------------------------------------
extern "C" void kernel_launch(void* const* d_in, const int* in_sizes, int n_in,
                              void* d_out, int out_size, void* d_ws, size_t ws_size,
                              hipStream_t stream) {
    (void)in_sizes; (void)n_in; (void)out_size;
    const float* x      = (const float*)d_in[0];
    const float* omega0 = (const float*)d_in[1];
    float* outp = (float*)d_out;
    char* ws = (char*)d_ws;

    const size_t MB = (size_t)1 << 20;
    float2* fhat   = (float2*)(ws);                  // 8 MB (scrambled order)
    float2* lamOut = (float2*)(ws + 8 * MB);         // 8 MB
    ull*    rec    = (ull*)(ws + 16 * MB);           // 2 slots * 8*CNB u64
    float*  oom    = (float*)(ws + 16 * MB + 64 * 1024);  // 3 floats
    const bool batch3 = ws_size >= 66 * MB;
    float2* sA = (float2*)(ws + 17 * MB);            // 24 or 8 MB
    float2* sB = batch3 ? (float2*)(ws + 41 * MB)
                        : (float2*)(ws + 25 * MB);

    dim3 tb(32, 8);
    dim3 tg(32, 32);

    // forward FFT of (-1)^n*x -> fhat in scrambled order (4 passes)
    k_tr_fwd_in<<<tg, tb, 0, stream>>>(x, sA);
    k_fft1024<<<1024, 256, 0, stream>>>(sA, sB, -1.0f, 1);
    k_tr_c2c<<<tg, tb, 0, stream>>>(sB, sA);
    k_fft1024<<<1024, 256, 0, stream>>>(sA, fhat, -1.0f, 0);

    // all 50 VMD iterations in one cooperative kernel, state in registers
    {
        void* kargs[] = {(void*)&fhat, (void*)&omega0, (void*)&lamOut,
                         (void*)&rec, (void*)&oom};
        hipLaunchCooperativeKernel((const void*)k_vmd_all,
                                   dim3(CNB), dim3(CNT), kargs, 0, stream);
    }

    // inverse FFTs of u_k (u fused into first pass), output (-1)^n*Re(.)/N
    if (batch3) {
        k_fftu<<<3072, 256, 0, stream>>>(fhat, lamOut, oom, sB, 0);
        k_tr_c2c<<<dim3(32, 32, 3), tb, 0, stream>>>(sB, sA);
        k_fft1024<<<3072, 256, 0, stream>>>(sA, sB, 1.0f, 0);
        k_tr_out<<<dim3(32, 32, 3), tb, 0, stream>>>(sB, outp);
    } else {
        for (int k = 0; k < 3; ++k) {
            k_fftu<<<1024, 256, 0, stream>>>(fhat, lamOut, oom, sB, k);
            k_tr_c2c<<<tg, tb, 0, stream>>>(sB, sA);
            k_fft1024<<<1024, 256, 0, stream>>>(sA, sB, 1.0f, 0);
            k_tr_out<<<tg, tb, 0, stream>>>(sB, outp + (size_t)k * TN);
        }
    }
}

// Round 8
// 295.757 us; speedup vs baseline: 6.0254x; 1.3849x over previous
//
#include <hip/hip_runtime.h>
#include <math.h>

// ---------------------------------------------------------------------------
// VMD, T = 2^20, K = 3.  u[k][t] = (f_hat[t] - lam[t]/2) * g_k(t), g_k real.
// fftshift folded into (-1)^n input modulation; ifftshift into (-1)^n output.
//
// Round-8: the 50-iteration grid-wide loop is GONE.  Rounds 4-7 showed a
// ~5us/iter fixed cost for any 256-block barrier (max-block jitter + LLC
// visibility), 50x serialized.  Key reductions:
//  (1) tau=1e-7 => |lam/2fhat| <= 5e-6: lam is numerically irrelevant to the
//      omega dynamics (1e-5 relative on power sums, 3 orders below the 1.16e-2
//      threshold).  lam kept exactly to 1st order in the OUTPUT via
//      S(fr) = sum_i(gs(fr,om_i)-1), lam = tau*fhat*S.
//  (2) with lam dropped, every per-iteration sum is sum_t m2(t)*G(fr_t,om)
//      with m2=|fhat|^2 iteration-invariant => compress the spectrum into
//      2048 bins (B_j, first moment M1_j); M1 linear correction makes the
//      binning error O((h/w)^2)~4e-5 relative => d(omega)~1e-7/step.
// The whole loop runs in ONE block over LDS/register-resident bins: no grid
// sync, no cooperative launch, no atomics.  11 total dispatches.
// ---------------------------------------------------------------------------

#define TN        (1 << 20)
#define NBINS     2048
#define PPB       512          // points per bin (TN/NBINS)
#define FALPHA    2000.0f
#define FTAU      1e-7f
#define FTOL      1e-6f
#define FEPS      1e-8f
#define FTWO_PI   6.28318530717958647692f
#define FINV_T    (1.0f / 1048576.0f)

__device__ __forceinline__ float2 cmulf(float2 a, float2 b) {
    return make_float2(a.x * b.x - a.y * b.y, a.x * b.y + a.y * b.x);
}
__device__ __forceinline__ float2 cisf(float a) {
    float s, c;
    __sincosf(a, &s, &c);     // HW v_sin/v_cos; |err| ~1e-6, fine vs margin
    return make_float2(c, s);
}

// g_k(fr) for K=3 with neighbor coupling (stale omega, like the reference)
__device__ __forceinline__ void g3f(float fr, float om0, float om1, float om2,
                                    float& g0, float& g1, float& g2) {
    const float tau2 = FTAU * FTAU;
    float d0 = fr - om0; d0 *= d0;
    float d1 = fr - om1; d1 *= d1;
    float d2 = fr - om2; d2 *= d2;
    g0 = __builtin_amdgcn_rcpf(1.0f + FALPHA * (d0 + d1 + tau2));
    g1 = __builtin_amdgcn_rcpf(1.0f + FALPHA * (d0 + d1 + d2 + tau2));
    g2 = __builtin_amdgcn_rcpf(1.0f + FALPHA * (d1 + d2 + tau2));
}

// ---------------------------------------------------------------------------
// m2 transpose: m2_true[t] = |fhat_scrambled[q]|^2  (q<->t is the 1024x1024
// row/col swap, so this is exactly the standard LDS-tiled transpose)
// ---------------------------------------------------------------------------
__global__ __launch_bounds__(256)
void k_m2tr(const float2* __restrict__ in, float* __restrict__ out) {
    __shared__ float tile[32][33];
    const int bx = blockIdx.x * 32, by = blockIdx.y * 32;
    const int tx = threadIdx.x, ty = threadIdx.y;
#pragma unroll
    for (int j = 0; j < 32; j += 8) {
        const float2 v = in[(size_t)(by + ty + j) * 1024 + bx + tx];
        tile[ty + j][tx] = v.x * v.x + v.y * v.y;
    }
    __syncthreads();
#pragma unroll
    for (int j = 0; j < 32; j += 8)
        out[(size_t)(bx + ty + j) * 1024 + by + tx] = tile[tx][ty + j];
}

// ---------------------------------------------------------------------------
// histogram: per bin j (512 contiguous true-order points):
//   B[j]  = sum m2,   M1[j] = sum m2*(fr - c_j),  c_j = bin-mean of fr.
// block = 256 threads, 8192 points (16 bins); fully deterministic.
// ---------------------------------------------------------------------------
__global__ __launch_bounds__(256)
void k_hist(const float4* __restrict__ m2, float* __restrict__ Bb,
            float* __restrict__ M1b) {
    __shared__ float accB[16][4];
    __shared__ float accM[16][4];
    const int tid = threadIdx.x;
    const int lane = tid & 63, wid = tid >> 6;
    if (tid < 64) { accB[tid >> 2][tid & 3] = 0.f; accM[tid >> 2][tid & 3] = 0.f; }
    __syncthreads();
    const size_t base4 = (size_t)blockIdx.x * 2048;   // float4 index
    const float h = FINV_T;
    // d0 = (t&511 - 255.5)/T ; exact (both operands exact, result tiny)
    const float d0 = ((float)((tid * 4) & 511) - 255.5f) * FINV_T;
#pragma unroll
    for (int i = 0; i < 8; ++i) {
        const float4 v = m2[base4 + (size_t)i * 256 + tid];
        float s  = v.x + v.y + v.z + v.w;
        float m1 = d0 * s + h * (v.y + 2.f * v.z + 3.f * v.w);
#pragma unroll
        for (int off = 32; off > 0; off >>= 1) {
            s  += __shfl_down(s, off);
            m1 += __shfl_down(m1, off);
        }
        if (lane == 0) {
            const int bl = i * 2 + (wid >> 1);   // bin_local, uniform per wave
            accB[bl][wid] += s;
            accM[bl][wid] += m1;
        }
    }
    __syncthreads();
    if (tid < 16) {
        const int gb = blockIdx.x * 16 + tid;
        Bb[gb]  = accB[tid][0] + accB[tid][1] + accB[tid][2] + accB[tid][3];
        M1b[gb] = accM[tid][0] + accM[tid][1] + accM[tid][2] + accM[tid][3];
    }
}

// ---------------------------------------------------------------------------
// single-block omega iteration over 2048 bins (register-resident per thread).
// Per bin & k: P_k = g^2*B + (g^2)'*M1,  W_k = c*P_k + g^2*M1,
// (g^2)' = -4*alpha*Dp_k*g^3.  Check iters add bin-center u_diff sums.
// sgs accumulates sum_i(gs_i - 1) for the first-order lam reconstruction.
// ---------------------------------------------------------------------------
__global__ __launch_bounds__(1024)
void k_omega(const float* __restrict__ Bb, const float* __restrict__ M1b,
             const float* __restrict__ omega0,
             float* __restrict__ oomf, float* __restrict__ sgsb) {
    const int tid = threadIdx.x;
    const int lane = tid & 63, wid = tid >> 6;
    const int j0 = tid * 2, j1 = j0 + 1;
    const float b0 = Bb[j0], b1 = Bb[j1];
    const float q0 = M1b[j0], q1 = M1b[j1];
    const float c0 = ((float)(j0 * PPB) + 255.5f) * FINV_T - 0.5f;
    const float c1 = ((float)(j1 * PPB) + 255.5f) * FINV_T - 0.5f;
    const float kA = -4.0f * FALPHA;

    float om0 = 0.5f * omega0[0];
    float om1 = 0.5f * omega0[1];
    float om2 = 0.5f * omega0[2];
    float op0 = om0, op1 = om1, op2 = om2;
    float sg0 = 0.f, sg1 = 0.f, gp0 = 0.f, gp1 = 0.f;

    __shared__ float wred[16][8];
    __shared__ float osh[4];
    bool fin = true;

    for (int n = 0; n < 49; ++n) {
        if (n > 0) {
            if (osh[3] != 0.f) { fin = false; break; }
            op0 = om0; op1 = om1; op2 = om2;
            om0 = osh[0]; om1 = osh[1]; om2 = osh[2];
            sg0 += gp0 - 1.0f;               // adds gs_{n-1}
            sg1 += gp1 - 1.0f;
        }
        const int check = (n > 0 && n % 10 == 0);

        float a[8];
#pragma unroll
        for (int v = 0; v < 8; ++v) a[v] = 0.f;

#pragma unroll
        for (int bb = 0; bb < 2; ++bb) {
            const float c  = bb ? c1 : c0;
            const float B  = bb ? b1 : b0;
            const float M1 = bb ? q1 : q0;
            const float e0 = c - om0, e1 = c - om1, e2 = c - om2;
            float g0, g1, g2;
            g3f(c, om0, om1, om2, g0, g1, g2);
            const float gsq0 = g0 * g0, gsq1 = g1 * g1, gsq2 = g2 * g2;
            const float gc0 = gsq0 * g0, gc1 = gsq1 * g1, gc2 = gsq2 * g2;
            const float Dp0 = e0 + e1, Dp1 = e0 + e1 + e2, Dp2 = e1 + e2;
            const float P0 = gsq0 * B + kA * Dp0 * gc0 * M1;
            const float P1 = gsq1 * B + kA * Dp1 * gc1 * M1;
            const float P2 = gsq2 * B + kA * Dp2 * gc2 * M1;
            a[0] += P0; a[1] += P1; a[2] += P2;
            a[3] += c * P0 + gsq0 * M1;
            a[4] += c * P1 + gsq1 * M1;
            a[5] += c * P2 + gsq2 * M1;
            const float gs = g0 + g1 + g2;
            if (bb) gp1 = gs; else gp0 = gs;
            if (check) {                      // bin-center u_diff sums
                float h0, h1, h2;
                g3f(c, op0, op1, op2, h0, h1, h2);
                const float d0 = g0 - h0, d1 = g1 - h1, d2 = g2 - h2;
                a[6] += B * (d0 * d0 + d1 * d1 + d2 * d2);
                a[7] += B * (h0 * h0 + h1 * h1 + h2 * h2);
            }
        }
#pragma unroll
        for (int off = 32; off > 0; off >>= 1) {
#pragma unroll
            for (int v = 0; v < 8; ++v) a[v] += __shfl_down(a[v], off);
        }
        if (lane == 0) {
#pragma unroll
            for (int v = 0; v < 8; ++v) wred[wid][v] = a[v];
        }
        __syncthreads();
        if (tid == 0) {
            double S[8];
#pragma unroll
            for (int v = 0; v < 8; ++v) {
                double s = 0.0;
#pragma unroll
                for (int w = 0; w < 16; ++w) s += (double)wred[w][v];
                S[v] = s;
            }
            const float n0 = (float)(S[3] / (S[0] + (double)FEPS));
            const float n1 = (float)(S[4] / (S[1] + (double)FEPS));
            const float n2 = (float)(S[5] / (S[2] + (double)FEPS));
            float stop = 0.f;
            if (check) {
                const double ud = S[6] / (S[7] + (double)FEPS);
                const float od = (fabsf(n0 - n2) + fabsf(n1 - n0) +
                                  fabsf(n2 - n1)) * (1.0f / 3.0f);
                if (ud < (double)FTOL && od < FTOL) stop = 1.f;
            }
            osh[0] = n0; osh[1] = n1; osh[2] = n2; osh[3] = stop;
        }
        __syncthreads();
    }

    if (fin) {                 // completed: omega entering iter 49, sgs 0..48
        sg0 += gp0 - 1.0f;
        sg1 += gp1 - 1.0f;
        om0 = osh[0]; om1 = osh[1]; om2 = osh[2];
    }
    sgsb[j0] = sg0;
    sgsb[j1] = sg1;
    if (tid == 0) { oomf[0] = om0; oomf[1] = om1; oomf[2] = om2; }
}

// ---------------------------------------------------------------------------
// 1024-point Stockham radix-4 stages in LDS (caller loads bufA, then syncs)
// ---------------------------------------------------------------------------
__device__ __forceinline__ float2* fft1024_stages(float2* bufA, float2* bufB,
                                                  int t, float dir) {
    float2* src = bufA;
    float2* dst = bufB;
    int Ns = 1;
#pragma unroll
    for (int s = 0; s < 5; ++s) {
        const int jm = t & (Ns - 1);
        float2 v0 = src[t], v1 = src[t + 256], v2 = src[t + 512], v3 = src[t + 768];
        const float a = dir * (FTWO_PI * 0.25f) * ((float)jm / (float)Ns);
        float2 w1 = cisf(a);
        float2 w2 = cmulf(w1, w1);
        float2 w3 = cmulf(w2, w1);
        v1 = cmulf(v1, w1); v2 = cmulf(v2, w2); v3 = cmulf(v3, w3);
        float2 s0 = make_float2(v0.x + v2.x, v0.y + v2.y);
        float2 s1 = make_float2(v0.x - v2.x, v0.y - v2.y);
        float2 s2 = make_float2(v1.x + v3.x, v1.y + v3.y);
        float2 s3 = make_float2(v1.x - v3.x, v1.y - v3.y);
        float2 s3i = make_float2(-dir * s3.y, dir * s3.x);  // dir*i * s3
        const int base = ((t - jm) << 2) + jm;
        dst[base]          = make_float2(s0.x + s2.x, s0.y + s2.y);
        dst[base + Ns]     = make_float2(s1.x + s3i.x, s1.y + s3i.y);
        dst[base + 2 * Ns] = make_float2(s0.x - s2.x, s0.y - s2.y);
        dst[base + 3 * Ns] = make_float2(s1.x - s3i.x, s1.y - s3i.y);
        __syncthreads();
        float2* tmp = src; src = dst; dst = tmp;
        Ns <<= 2;
    }
    return src;
}

// generic row FFT: dir=-1 fwd / +1 inv; do_tw: * e^{dir*2pi*i*row*col/2^20}
__global__ __launch_bounds__(256)
void k_fft1024(const float2* __restrict__ in, float2* __restrict__ out,
               float dir, int do_tw) {
    __shared__ float2 bufA[1024];
    __shared__ float2 bufB[1024];
    const int row  = blockIdx.x;
    const int rowm = row & 1023;
    const float2* __restrict__ rin  = in  + (size_t)row * 1024;
    float2* __restrict__ rout = out + (size_t)row * 1024;
    const int t = threadIdx.x;
#pragma unroll
    for (int r = 0; r < 4; ++r) bufA[t + 256 * r] = rin[t + 256 * r];
    __syncthreads();
    float2* src = fft1024_stages(bufA, bufB, t, dir);
#pragma unroll
    for (int r = 0; r < 4; ++r) {
        const int c = t + 256 * r;
        float2 xv = src[c];
        if (do_tw) {
            const unsigned p = ((unsigned)rowm * (unsigned)c) & 1048575u;
            xv = cmulf(xv, cisf(dir * (FTWO_PI * FINV_T) * (float)p));
        }
        rout[c] = xv;
    }
}

// first inverse-FFT pass with u-compute fused into the load stage.
// u = fhat * (1 - tau*sgs/2) * g_k ; scrambled row `row` IS the k2-row the
// inverse six-step needs.  bin(t) = t>>9 with t = (c<<10)|row.
__global__ __launch_bounds__(256)
void k_fftu(const float2* __restrict__ fhat, const float* __restrict__ sgsb,
            const float* __restrict__ oomf,
            float2* __restrict__ out, int kbase) {
    __shared__ float2 bufA[1024];
    __shared__ float2 bufB[1024];
    const int row = blockIdx.x & 1023;
    const int z   = blockIdx.x >> 10;
    const int kk  = kbase + z;
    const float om0 = oomf[0], om1 = oomf[1], om2 = oomf[2];
    const float2* __restrict__ frow = fhat + (size_t)row * 1024;
    const int rb = row >> 9;
    const int t = threadIdx.x;
#pragma unroll
    for (int r = 0; r < 4; ++r) {
        const int c = t + 256 * r;
        const float2 f = frow[c];
        const float sgv = sgsb[(c << 1) | rb];
        const float sc = 1.0f - 0.5f * FTAU * sgv;
        const float cr = f.x * sc;
        const float ci = f.y * sc;
        const float fr = (float)((c << 10) | row) * FINV_T - 0.5f;
        float g0, g1, g2;
        g3f(fr, om0, om1, om2, g0, g1, g2);
        const float g = (kk == 0) ? g0 : ((kk == 1) ? g1 : g2);
        bufA[c] = make_float2(cr * g, ci * g);
    }
    __syncthreads();
    float2* src = fft1024_stages(bufA, bufB, t, 1.0f);
    float2* __restrict__ rout = out + (size_t)z * TN + (size_t)row * 1024;
#pragma unroll
    for (int r = 0; r < 4; ++r) {
        const int c = t + 256 * r;
        const unsigned p = ((unsigned)row * (unsigned)c) & 1048575u;
        rout[c] = cmulf(src[c], cisf((FTWO_PI * FINV_T) * (float)p));
    }
}

// ---------------------------------------------------------------------------
// transposes (32x32 LDS tiles, block (32,8)); grid z = batch
// ---------------------------------------------------------------------------
__global__ __launch_bounds__(256)
void k_tr_c2c(const float2* __restrict__ in, float2* __restrict__ out) {
    __shared__ float2 tile[32][33];
    const size_t zo = (size_t)blockIdx.z * TN;
    const int bx = blockIdx.x * 32, by = blockIdx.y * 32;
    const int tx = threadIdx.x, ty = threadIdx.y;
#pragma unroll
    for (int j = 0; j < 32; j += 8)
        tile[ty + j][tx] = in[zo + (size_t)(by + ty + j) * 1024 + bx + tx];
    __syncthreads();
#pragma unroll
    for (int j = 0; j < 32; j += 8)
        out[zo + (size_t)(bx + ty + j) * 1024 + by + tx] = tile[tx][ty + j];
}

// forward input: y = (-1)^n * x, transposed, real -> complex
__global__ __launch_bounds__(256)
void k_tr_fwd_in(const float* __restrict__ in, float2* __restrict__ out) {
    __shared__ float tile[32][33];
    const int bx = blockIdx.x * 32, by = blockIdx.y * 32;
    const int tx = threadIdx.x, ty = threadIdx.y;
#pragma unroll
    for (int j = 0; j < 32; j += 8)
        tile[ty + j][tx] = in[(size_t)(by + ty + j) * 1024 + bx + tx];
    __syncthreads();
#pragma unroll
    for (int j = 0; j < 32; j += 8) {
        const int r = bx + ty + j;
        float v = tile[tx][ty + j];
        v = (r & 1) ? -v : v;
        out[(size_t)r * 1024 + by + tx] = make_float2(v, 0.0f);
    }
}

// inverse output: imf = (-1)^n * (1/N) * Re(.), transposed store
__global__ __launch_bounds__(256)
void k_tr_out(const float2* __restrict__ in, float* __restrict__ out) {
    __shared__ float2 tile[32][33];
    const size_t zo = (size_t)blockIdx.z * TN;
    const int bx = blockIdx.x * 32, by = blockIdx.y * 32;
    const int tx = threadIdx.x, ty = threadIdx.y;
#pragma unroll
    for (int j = 0; j < 32; j += 8)
        tile[ty + j][tx] = in[zo + (size_t)(by + ty + j) * 1024 + bx + tx];
    __syncthreads();
    const int c = by + tx;
    const float sgn = (c & 1) ? -FINV_T : FINV_T;
#pragma unroll
    for (int j = 0; j < 32; j += 8) {
        const int r = bx + ty + j;
        out[zo + (size_t)r * 1024 + c] = tile[tx][ty + j].x * sgn;
    }
}

// ---------------------------------------------------------------------------
extern "C" void kernel_launch(void* const* d_in, const int* in_sizes, int n_in,
                              void* d_out, int out_size, void* d_ws, size_t ws_size,
                              hipStream_t stream) {
    (void)in_sizes; (void)n_in; (void)out_size;
    const float* x      = (const float*)d_in[0];
    const float* omega0 = (const float*)d_in[1];
    float* outp = (float*)d_out;
    char* ws = (char*)d_ws;

    const size_t MB = (size_t)1 << 20;
    const size_t KB = (size_t)1 << 10;
    float2* fhat = (float2*)(ws);                    // 8 MB (scrambled order)
    float*  m2   = (float*)(ws + 8 * MB);            // 4 MB (true order)
    float*  Bb   = (float*)(ws + 12 * MB);           // 8 KB
    float*  M1b  = (float*)(ws + 12 * MB + 8 * KB);  // 8 KB
    float*  sgsb = (float*)(ws + 12 * MB + 16 * KB); // 8 KB
    float*  oomf = (float*)(ws + 12 * MB + 24 * KB); // 3 floats
    const bool batch3 = ws_size >= 62 * MB;
    float2* sA = (float2*)(ws + 13 * MB);            // 24 or 8 MB
    float2* sB = batch3 ? (float2*)(ws + 37 * MB)
                        : (float2*)(ws + 21 * MB);

    dim3 tb(32, 8);
    dim3 tg(32, 32);

    // forward FFT of (-1)^n*x -> fhat in scrambled order (4 passes)
    k_tr_fwd_in<<<tg, tb, 0, stream>>>(x, sA);
    k_fft1024<<<1024, 256, 0, stream>>>(sA, sB, -1.0f, 1);
    k_tr_c2c<<<tg, tb, 0, stream>>>(sB, sA);
    k_fft1024<<<1024, 256, 0, stream>>>(sA, fhat, -1.0f, 0);

    // spectrum compression: m2 (true order) -> 2048-bin {B, M1}
    k_m2tr<<<tg, tb, 0, stream>>>(fhat, m2);
    k_hist<<<TN / 8192, 256, 0, stream>>>((const float4*)m2, Bb, M1b);

    // all 50 omega iterations in ONE block over the bins
    k_omega<<<1, 1024, 0, stream>>>(Bb, M1b, omega0, oomf, sgsb);

    // inverse FFTs of u_k (u fused into first pass), output (-1)^n*Re(.)/N
    if (batch3) {
        k_fftu<<<3072, 256, 0, stream>>>(fhat, sgsb, oomf, sB, 0);
        k_tr_c2c<<<dim3(32, 32, 3), tb, 0, stream>>>(sB, sA);
        k_fft1024<<<3072, 256, 0, stream>>>(sA, sB, 1.0f, 0);
        k_tr_out<<<dim3(32, 32, 3), tb, 0, stream>>>(sB, outp);
    } else {
        for (int k = 0; k < 3; ++k) {
            k_fftu<<<1024, 256, 0, stream>>>(fhat, sgsb, oomf, sB, k);
            k_tr_c2c<<<tg, tb, 0, stream>>>(sB, sA);
            k_fft1024<<<1024, 256, 0, stream>>>(sA, sB, 1.0f, 0);
            k_tr_out<<<tg, tb, 0, stream>>>(sB, outp + (size_t)k * TN);
        }
    }
}

// Round 9
// 209.533 us; speedup vs baseline: 8.5049x; 1.4115x over previous
//
#include <hip/hip_runtime.h>
#include <math.h>

// ---------------------------------------------------------------------------
// VMD, T = 2^20, K = 3.  u[k][t] = (f_hat[t] - lam[t]/2) * g_k(t), g_k real.
// fftshift folded into (-1)^n input modulation; ifftshift into (-1)^n output.
//
// Round-9: round-8 collapsed the 50 grid-wide iterations into one tiny
// single-block kernel over a 2048-bin compressed spectrum -- but that kernel
// ran at 170us because __shfl_down lowers to ds_bpermute (~120cyc LDS pipe,
// serialized by per-use waitcnt: 48 shuffles/iter ~ 2.4us) plus a serial
// double-precision tail.  Now the wave reduce is the classic gfx9 DPP
// sequence (row_shr 1/2/4/8 + row_bcast 15/31 -- 6 VALU adds, sum in lane
// 63), 256 threads / 4 waves (8 bins per thread), and the serial stage is
// 32 f32 adds + 3 f32 divides (reference computes in f32 anyway).
// ---------------------------------------------------------------------------

#define TN        (1 << 20)
#define NBINS     2048
#define PPB       512          // points per bin (TN/NBINS)
#define FALPHA    2000.0f
#define FTAU      1e-7f
#define FTOL      1e-6f
#define FEPS      1e-8f
#define FTWO_PI   6.28318530717958647692f
#define FINV_T    (1.0f / 1048576.0f)

__device__ __forceinline__ float2 cmulf(float2 a, float2 b) {
    return make_float2(a.x * b.x - a.y * b.y, a.x * b.y + a.y * b.x);
}
__device__ __forceinline__ float2 cisf(float a) {
    float s, c;
    __sincosf(a, &s, &c);     // HW v_sin/v_cos; |err| ~1e-6, fine vs margin
    return make_float2(c, s);
}

// g_k(fr) for K=3 with neighbor coupling (stale omega, like the reference)
__device__ __forceinline__ void g3f(float fr, float om0, float om1, float om2,
                                    float& g0, float& g1, float& g2) {
    const float tau2 = FTAU * FTAU;
    float d0 = fr - om0; d0 *= d0;
    float d1 = fr - om1; d1 *= d1;
    float d2 = fr - om2; d2 *= d2;
    g0 = __builtin_amdgcn_rcpf(1.0f + FALPHA * (d0 + d1 + tau2));
    g1 = __builtin_amdgcn_rcpf(1.0f + FALPHA * (d0 + d1 + d2 + tau2));
    g2 = __builtin_amdgcn_rcpf(1.0f + FALPHA * (d1 + d2 + tau2));
}

// wave64 sum via DPP (VALU-speed, no LDS): result valid in lane 63.
// row_shr:{1,2,4,8} builds 16-lane row prefix sums; row_bcast:15 merges
// row0->row1 / row2->row3; row_bcast:31 merges lower half into lane 63.
__device__ __forceinline__ float dpp_wave_sum(float x) {
    x += __int_as_float(__builtin_amdgcn_update_dpp(
             0, __float_as_int(x), 0x111, 0xf, 0xf, true));  // row_shr:1
    x += __int_as_float(__builtin_amdgcn_update_dpp(
             0, __float_as_int(x), 0x112, 0xf, 0xf, true));  // row_shr:2
    x += __int_as_float(__builtin_amdgcn_update_dpp(
             0, __float_as_int(x), 0x114, 0xf, 0xf, true));  // row_shr:4
    x += __int_as_float(__builtin_amdgcn_update_dpp(
             0, __float_as_int(x), 0x118, 0xf, 0xf, true));  // row_shr:8
    x += __int_as_float(__builtin_amdgcn_update_dpp(
             0, __float_as_int(x), 0x142, 0xf, 0xf, true));  // row_bcast:15
    x += __int_as_float(__builtin_amdgcn_update_dpp(
             0, __float_as_int(x), 0x143, 0xf, 0xf, true));  // row_bcast:31
    return x;
}

// ---------------------------------------------------------------------------
// m2 transpose: m2_true[t] = |fhat_scrambled[q]|^2  (q<->t is the 1024x1024
// row/col swap, so this is exactly the standard LDS-tiled transpose)
// ---------------------------------------------------------------------------
__global__ __launch_bounds__(256)
void k_m2tr(const float2* __restrict__ in, float* __restrict__ out) {
    __shared__ float tile[32][33];
    const int bx = blockIdx.x * 32, by = blockIdx.y * 32;
    const int tx = threadIdx.x, ty = threadIdx.y;
#pragma unroll
    for (int j = 0; j < 32; j += 8) {
        const float2 v = in[(size_t)(by + ty + j) * 1024 + bx + tx];
        tile[ty + j][tx] = v.x * v.x + v.y * v.y;
    }
    __syncthreads();
#pragma unroll
    for (int j = 0; j < 32; j += 8)
        out[(size_t)(bx + ty + j) * 1024 + by + tx] = tile[tx][ty + j];
}

// ---------------------------------------------------------------------------
// histogram: per bin j (512 contiguous true-order points):
//   B[j]  = sum m2,   M1[j] = sum m2*(fr - c_j),  c_j = bin-mean of fr.
// block = 256 threads, 8192 points (16 bins); fully deterministic.
// ---------------------------------------------------------------------------
__global__ __launch_bounds__(256)
void k_hist(const float4* __restrict__ m2, float* __restrict__ Bb,
            float* __restrict__ M1b) {
    __shared__ float accB[16][4];
    __shared__ float accM[16][4];
    const int tid = threadIdx.x;
    const int lane = tid & 63, wid = tid >> 6;
    if (tid < 64) { accB[tid >> 2][tid & 3] = 0.f; accM[tid >> 2][tid & 3] = 0.f; }
    __syncthreads();
    const size_t base4 = (size_t)blockIdx.x * 2048;   // float4 index
    const float h = FINV_T;
    const float d0 = ((float)((tid * 4) & 511) - 255.5f) * FINV_T;
#pragma unroll
    for (int i = 0; i < 8; ++i) {
        const float4 v = m2[base4 + (size_t)i * 256 + tid];
        float s  = v.x + v.y + v.z + v.w;
        float m1 = d0 * s + h * (v.y + 2.f * v.z + 3.f * v.w);
#pragma unroll
        for (int off = 32; off > 0; off >>= 1) {
            s  += __shfl_down(s, off);
            m1 += __shfl_down(m1, off);
        }
        if (lane == 0) {
            const int bl = i * 2 + (wid >> 1);   // bin_local, uniform per wave
            accB[bl][wid] += s;
            accM[bl][wid] += m1;
        }
    }
    __syncthreads();
    if (tid < 16) {
        const int gb = blockIdx.x * 16 + tid;
        Bb[gb]  = accB[tid][0] + accB[tid][1] + accB[tid][2] + accB[tid][3];
        M1b[gb] = accM[tid][0] + accM[tid][1] + accM[tid][2] + accM[tid][3];
    }
}

// ---------------------------------------------------------------------------
// single-block omega iteration over 2048 bins, 256 threads x 8 bins.
// Per bin & k: P_k = g^2*B + (g^2)'*M1,  W_k = c*P_k + g^2*M1,
// (g^2)' = -4*alpha*Dp_k*g^3.  Check iters add bin-center u_diff sums.
// sgs accumulates sum_i(gs_i - 1) for the first-order lam reconstruction.
// ---------------------------------------------------------------------------
__global__ __launch_bounds__(256)
void k_omega(const float* __restrict__ Bb, const float* __restrict__ M1b,
             const float* __restrict__ omega0,
             float* __restrict__ oomf, float* __restrict__ sgsb) {
    const int tid = threadIdx.x;
    const int lane = tid & 63, wid = tid >> 6;   // 4 waves
    const float kA = -4.0f * FALPHA;

    float B[8], M[8], C[8], SG[8], gp[8];
#pragma unroll
    for (int i = 0; i < 8; ++i) {
        const int j = tid + 256 * i;
        B[i] = Bb[j];
        M[i] = M1b[j];
        C[i] = ((float)(j * PPB) + 255.5f) * FINV_T - 0.5f;
        SG[i] = 0.f;
        gp[i] = 0.f;
    }

    float om0 = 0.5f * omega0[0];
    float om1 = 0.5f * omega0[1];
    float om2 = 0.5f * omega0[2];
    float op0 = om0, op1 = om1, op2 = om2;

    __shared__ float wsum[4][8];
    __shared__ float osh[4];
    bool fin = true;

    for (int n = 0; n < 49; ++n) {
        if (n > 0) {
            if (osh[3] != 0.f) { fin = false; break; }
            op0 = om0; op1 = om1; op2 = om2;
            om0 = osh[0]; om1 = osh[1]; om2 = osh[2];
#pragma unroll
            for (int i = 0; i < 8; ++i) SG[i] += gp[i] - 1.0f;  // gs_{n-1}
        }
        const int check = (n > 0 && n % 10 == 0);

        float a[8];
#pragma unroll
        for (int v = 0; v < 8; ++v) a[v] = 0.f;

#pragma unroll
        for (int i = 0; i < 8; ++i) {
            const float c  = C[i];
            const float Bv = B[i];
            const float M1 = M[i];
            const float e0 = c - om0, e1 = c - om1, e2 = c - om2;
            float g0, g1, g2;
            g3f(c, om0, om1, om2, g0, g1, g2);
            const float gsq0 = g0 * g0, gsq1 = g1 * g1, gsq2 = g2 * g2;
            const float gc0 = gsq0 * g0, gc1 = gsq1 * g1, gc2 = gsq2 * g2;
            const float Dp0 = e0 + e1, Dp1 = e0 + e1 + e2, Dp2 = e1 + e2;
            const float P0 = gsq0 * Bv + kA * Dp0 * gc0 * M1;
            const float P1 = gsq1 * Bv + kA * Dp1 * gc1 * M1;
            const float P2 = gsq2 * Bv + kA * Dp2 * gc2 * M1;
            a[0] += P0; a[1] += P1; a[2] += P2;
            a[3] += c * P0 + gsq0 * M1;
            a[4] += c * P1 + gsq1 * M1;
            a[5] += c * P2 + gsq2 * M1;
            gp[i] = g0 + g1 + g2;
            if (check) {                      // bin-center u_diff sums
                float h0, h1, h2;
                g3f(c, op0, op1, op2, h0, h1, h2);
                const float d0 = g0 - h0, d1 = g1 - h1, d2 = g2 - h2;
                a[6] += Bv * (d0 * d0 + d1 * d1 + d2 * d2);
                a[7] += Bv * (h0 * h0 + h1 * h1 + h2 * h2);
            }
        }
        // VALU-speed wave reduce (sum lands in lane 63)
#pragma unroll
        for (int v = 0; v < 8; ++v) a[v] = dpp_wave_sum(a[v]);
        if (lane == 63) {
#pragma unroll
            for (int v = 0; v < 8; ++v) wsum[wid][v] = a[v];
        }
        __syncthreads();
        if (tid == 0) {
            float S[8];
#pragma unroll
            for (int v = 0; v < 8; ++v)
                S[v] = wsum[0][v] + wsum[1][v] + wsum[2][v] + wsum[3][v];
            const float n0 = S[3] / (S[0] + FEPS);
            const float n1 = S[4] / (S[1] + FEPS);
            const float n2 = S[5] / (S[2] + FEPS);
            float stop = 0.f;
            if (check) {
                const float ud = S[6] / (S[7] + FEPS);
                const float od = (fabsf(n0 - n2) + fabsf(n1 - n0) +
                                  fabsf(n2 - n1)) * (1.0f / 3.0f);
                if (ud < FTOL && od < FTOL) stop = 1.f;
            }
            osh[0] = n0; osh[1] = n1; osh[2] = n2; osh[3] = stop;
        }
        __syncthreads();
    }

    if (fin) {                 // completed: omega entering iter 49, sgs 0..48
#pragma unroll
        for (int i = 0; i < 8; ++i) SG[i] += gp[i] - 1.0f;
        om0 = osh[0]; om1 = osh[1]; om2 = osh[2];
    }
#pragma unroll
    for (int i = 0; i < 8; ++i) sgsb[tid + 256 * i] = SG[i];
    if (tid == 0) { oomf[0] = om0; oomf[1] = om1; oomf[2] = om2; }
}

// ---------------------------------------------------------------------------
// 1024-point Stockham radix-4 stages in LDS (caller loads bufA, then syncs)
// ---------------------------------------------------------------------------
__device__ __forceinline__ float2* fft1024_stages(float2* bufA, float2* bufB,
                                                  int t, float dir) {
    float2* src = bufA;
    float2* dst = bufB;
    int Ns = 1;
#pragma unroll
    for (int s = 0; s < 5; ++s) {
        const int jm = t & (Ns - 1);
        float2 v0 = src[t], v1 = src[t + 256], v2 = src[t + 512], v3 = src[t + 768];
        const float a = dir * (FTWO_PI * 0.25f) * ((float)jm / (float)Ns);
        float2 w1 = cisf(a);
        float2 w2 = cmulf(w1, w1);
        float2 w3 = cmulf(w2, w1);
        v1 = cmulf(v1, w1); v2 = cmulf(v2, w2); v3 = cmulf(v3, w3);
        float2 s0 = make_float2(v0.x + v2.x, v0.y + v2.y);
        float2 s1 = make_float2(v0.x - v2.x, v0.y - v2.y);
        float2 s2 = make_float2(v1.x + v3.x, v1.y + v3.y);
        float2 s3 = make_float2(v1.x - v3.x, v1.y - v3.y);
        float2 s3i = make_float2(-dir * s3.y, dir * s3.x);  // dir*i * s3
        const int base = ((t - jm) << 2) + jm;
        dst[base]          = make_float2(s0.x + s2.x, s0.y + s2.y);
        dst[base + Ns]     = make_float2(s1.x + s3i.x, s1.y + s3i.y);
        dst[base + 2 * Ns] = make_float2(s0.x - s2.x, s0.y - s2.y);
        dst[base + 3 * Ns] = make_float2(s1.x - s3i.x, s1.y - s3i.y);
        __syncthreads();
        float2* tmp = src; src = dst; dst = tmp;
        Ns <<= 2;
    }
    return src;
}

// generic row FFT: dir=-1 fwd / +1 inv; do_tw: * e^{dir*2pi*i*row*col/2^20}
__global__ __launch_bounds__(256)
void k_fft1024(const float2* __restrict__ in, float2* __restrict__ out,
               float dir, int do_tw) {
    __shared__ float2 bufA[1024];
    __shared__ float2 bufB[1024];
    const int row  = blockIdx.x;
    const int rowm = row & 1023;
    const float2* __restrict__ rin  = in  + (size_t)row * 1024;
    float2* __restrict__ rout = out + (size_t)row * 1024;
    const int t = threadIdx.x;
#pragma unroll
    for (int r = 0; r < 4; ++r) bufA[t + 256 * r] = rin[t + 256 * r];
    __syncthreads();
    float2* src = fft1024_stages(bufA, bufB, t, dir);
#pragma unroll
    for (int r = 0; r < 4; ++r) {
        const int c = t + 256 * r;
        float2 xv = src[c];
        if (do_tw) {
            const unsigned p = ((unsigned)rowm * (unsigned)c) & 1048575u;
            xv = cmulf(xv, cisf(dir * (FTWO_PI * FINV_T) * (float)p));
        }
        rout[c] = xv;
    }
}

// first inverse-FFT pass with u-compute fused into the load stage.
// u = fhat * (1 - tau*sgs/2) * g_k ; scrambled row `row` IS the k2-row the
// inverse six-step needs.  bin(t) = t>>9 with t = (c<<10)|row.
__global__ __launch_bounds__(256)
void k_fftu(const float2* __restrict__ fhat, const float* __restrict__ sgsb,
            const float* __restrict__ oomf,
            float2* __restrict__ out, int kbase) {
    __shared__ float2 bufA[1024];
    __shared__ float2 bufB[1024];
    const int row = blockIdx.x & 1023;
    const int z   = blockIdx.x >> 10;
    const int kk  = kbase + z;
    const float om0 = oomf[0], om1 = oomf[1], om2 = oomf[2];
    const float2* __restrict__ frow = fhat + (size_t)row * 1024;
    const int rb = row >> 9;
    const int t = threadIdx.x;
#pragma unroll
    for (int r = 0; r < 4; ++r) {
        const int c = t + 256 * r;
        const float2 f = frow[c];
        const float sgv = sgsb[(c << 1) | rb];
        const float sc = 1.0f - 0.5f * FTAU * sgv;
        const float cr = f.x * sc;
        const float ci = f.y * sc;
        const float fr = (float)((c << 10) | row) * FINV_T - 0.5f;
        float g0, g1, g2;
        g3f(fr, om0, om1, om2, g0, g1, g2);
        const float g = (kk == 0) ? g0 : ((kk == 1) ? g1 : g2);
        bufA[c] = make_float2(cr * g, ci * g);
    }
    __syncthreads();
    float2* src = fft1024_stages(bufA, bufB, t, 1.0f);
    float2* __restrict__ rout = out + (size_t)z * TN + (size_t)row * 1024;
#pragma unroll
    for (int r = 0; r < 4; ++r) {
        const int c = t + 256 * r;
        const unsigned p = ((unsigned)row * (unsigned)c) & 1048575u;
        rout[c] = cmulf(src[c], cisf((FTWO_PI * FINV_T) * (float)p));
    }
}

// ---------------------------------------------------------------------------
// transposes (32x32 LDS tiles, block (32,8)); grid z = batch
// ---------------------------------------------------------------------------
__global__ __launch_bounds__(256)
void k_tr_c2c(const float2* __restrict__ in, float2* __restrict__ out) {
    __shared__ float2 tile[32][33];
    const size_t zo = (size_t)blockIdx.z * TN;
    const int bx = blockIdx.x * 32, by = blockIdx.y * 32;
    const int tx = threadIdx.x, ty = threadIdx.y;
#pragma unroll
    for (int j = 0; j < 32; j += 8)
        tile[ty + j][tx] = in[zo + (size_t)(by + ty + j) * 1024 + bx + tx];
    __syncthreads();
#pragma unroll
    for (int j = 0; j < 32; j += 8)
        out[zo + (size_t)(bx + ty + j) * 1024 + by + tx] = tile[tx][ty + j];
}

// forward input: y = (-1)^n * x, transposed, real -> complex
__global__ __launch_bounds__(256)
void k_tr_fwd_in(const float* __restrict__ in, float2* __restrict__ out) {
    __shared__ float tile[32][33];
    const int bx = blockIdx.x * 32, by = blockIdx.y * 32;
    const int tx = threadIdx.x, ty = threadIdx.y;
#pragma unroll
    for (int j = 0; j < 32; j += 8)
        tile[ty + j][tx] = in[(size_t)(by + ty + j) * 1024 + bx + tx];
    __syncthreads();
#pragma unroll
    for (int j = 0; j < 32; j += 8) {
        const int r = bx + ty + j;
        float v = tile[tx][ty + j];
        v = (r & 1) ? -v : v;
        out[(size_t)r * 1024 + by + tx] = make_float2(v, 0.0f);
    }
}

// inverse output: imf = (-1)^n * (1/N) * Re(.), transposed store
__global__ __launch_bounds__(256)
void k_tr_out(const float2* __restrict__ in, float* __restrict__ out) {
    __shared__ float2 tile[32][33];
    const size_t zo = (size_t)blockIdx.z * TN;
    const int bx = blockIdx.x * 32, by = blockIdx.y * 32;
    const int tx = threadIdx.x, ty = threadIdx.y;
#pragma unroll
    for (int j = 0; j < 32; j += 8)
        tile[ty + j][tx] = in[zo + (size_t)(by + ty + j) * 1024 + bx + tx];
    __syncthreads();
    const int c = by + tx;
    const float sgn = (c & 1) ? -FINV_T : FINV_T;
#pragma unroll
    for (int j = 0; j < 32; j += 8) {
        const int r = bx + ty + j;
        out[zo + (size_t)r * 1024 + c] = tile[tx][ty + j].x * sgn;
    }
}

// ---------------------------------------------------------------------------
extern "C" void kernel_launch(void* const* d_in, const int* in_sizes, int n_in,
                              void* d_out, int out_size, void* d_ws, size_t ws_size,
                              hipStream_t stream) {
    (void)in_sizes; (void)n_in; (void)out_size;
    const float* x      = (const float*)d_in[0];
    const float* omega0 = (const float*)d_in[1];
    float* outp = (float*)d_out;
    char* ws = (char*)d_ws;

    const size_t MB = (size_t)1 << 20;
    const size_t KB = (size_t)1 << 10;
    float2* fhat = (float2*)(ws);                    // 8 MB (scrambled order)
    float*  m2   = (float*)(ws + 8 * MB);            // 4 MB (true order)
    float*  Bb   = (float*)(ws + 12 * MB);           // 8 KB
    float*  M1b  = (float*)(ws + 12 * MB + 8 * KB);  // 8 KB
    float*  sgsb = (float*)(ws + 12 * MB + 16 * KB); // 8 KB
    float*  oomf = (float*)(ws + 12 * MB + 24 * KB); // 3 floats
    const bool batch3 = ws_size >= 62 * MB;
    float2* sA = (float2*)(ws + 13 * MB);            // 24 or 8 MB
    float2* sB = batch3 ? (float2*)(ws + 37 * MB)
                        : (float2*)(ws + 21 * MB);

    dim3 tb(32, 8);
    dim3 tg(32, 32);

    // forward FFT of (-1)^n*x -> fhat in scrambled order (4 passes)
    k_tr_fwd_in<<<tg, tb, 0, stream>>>(x, sA);
    k_fft1024<<<1024, 256, 0, stream>>>(sA, sB, -1.0f, 1);
    k_tr_c2c<<<tg, tb, 0, stream>>>(sB, sA);
    k_fft1024<<<1024, 256, 0, stream>>>(sA, fhat, -1.0f, 0);

    // spectrum compression: m2 (true order) -> 2048-bin {B, M1}
    k_m2tr<<<tg, tb, 0, stream>>>(fhat, m2);
    k_hist<<<TN / 8192, 256, 0, stream>>>((const float4*)m2, Bb, M1b);

    // all 49 omega updates in ONE small block over the bins
    k_omega<<<1, 256, 0, stream>>>(Bb, M1b, omega0, oomf, sgsb);

    // inverse FFTs of u_k (u fused into first pass), output (-1)^n*Re(.)/N
    if (batch3) {
        k_fftu<<<3072, 256, 0, stream>>>(fhat, sgsb, oomf, sB, 0);
        k_tr_c2c<<<dim3(32, 32, 3), tb, 0, stream>>>(sB, sA);
        k_fft1024<<<3072, 256, 0, stream>>>(sA, sB, 1.0f, 0);
        k_tr_out<<<dim3(32, 32, 3), tb, 0, stream>>>(sB, outp);
    } else {
        for (int k = 0; k < 3; ++k) {
            k_fftu<<<1024, 256, 0, stream>>>(fhat, sgsb, oomf, sB, k);
            k_tr_c2c<<<tg, tb, 0, stream>>>(sB, sA);
            k_fft1024<<<1024, 256, 0, stream>>>(sA, sB, 1.0f, 0);
            k_tr_out<<<tg, tb, 0, stream>>>(sB, outp + (size_t)k * TN);
        }
    }
}